// Round 1
// baseline (17537.344 us; speedup 1.0000x reference)
//
#include <hip/hip_runtime.h>
#include <hip/hip_bf16.h>
#include <math.h>

// Problem dims (fixed)
//  B=64, steps=20 (T=21), L=36, E=512, H=512, F=1024, VOC=20000
//  att_in = 2048 (h2|x_t|v_mean), lang_in = 1536 (mix|h1), 3H = 1536

typedef __attribute__((ext_vector_type(8))) short bf16x8;
typedef __attribute__((ext_vector_type(4))) float f32x4;

__device__ __forceinline__ unsigned short f2bf(float f){
  unsigned int u = __float_as_uint(f);
  u += 0x7fffu + ((u >> 16) & 1u);
  return (unsigned short)(u >> 16);
}
__device__ __forceinline__ float sigm(float x){ return 1.0f / (1.0f + __expf(-x)); }

// ---------------- workspace layout (bytes) ----------------
#define OFF_CNT     ((size_t)0)                      // int barrier counter (256 B pad)
#define OFF_H1A     ((size_t)256)                    // 64*512 f32
#define OFF_H1B     (OFF_H1A + 131072)
#define OFF_H2      (OFF_H1B + 131072)
#define OFF_MIX     (OFF_H2  + 131072)               // 64*1024 f32
#define OFF_VMEAN   (OFF_MIX + 262144)               // 64*1024 f32
#define OFF_VMW     (OFF_VMEAN + 262144)             // 64*1536 f32 (b_ih + v_mean@Wr^T)
#define OFF_VW      (OFF_VMW + 393216)               // 64*36*128 f32
#define OFF_G2      (OFF_VW + 1179648)               // [1536][64] f32 (b_lang_ih + h1@lwB^T)
#define OFF_GHH2    (OFF_G2 + 393216)                // [1536][64] f32 (b_lang_hh + h2@lwhh^T)
#define OFF_PREX    (OFF_GHH2 + 393216)              // [1344][1536] f32 (x_t@Wmid^T)
#define OFF_GTBF    (OFF_PREX + 8257536)             // 1344*512 bf16
#define OFF_WMIDBF  (OFF_GTBF + 1376256)             // 1536*512 bf16
#define OFF_H2BF    (OFF_WMIDBF + 1572864)           // 1280*512 bf16
#define OFF_WDBF    (OFF_H2BF + 1310720)             // 20000*512 bf16
// total ~34.6 MB

// ---------------- grid barrier (monotonic generation counter) ----------------
__device__ __forceinline__ void gbar(int* cnt, int target){
  __syncthreads();
  if (threadIdx.x == 0){
    __hip_atomic_fetch_add(cnt, 1, __ATOMIC_RELEASE, __HIP_MEMORY_SCOPE_AGENT);
    while (__hip_atomic_load(cnt, __ATOMIC_RELAXED, __HIP_MEMORY_SCOPE_AGENT) < target){
      __builtin_amdgcn_s_sleep(2);
    }
    // acquire to invalidate caches before consuming other blocks' data
    (void)__hip_atomic_load(cnt, __ATOMIC_ACQUIRE, __HIP_MEMORY_SCOPE_AGENT);
  }
  __syncthreads();
}

// ---------------- prep0: zeros + bf16 conversions + v_mean ----------------
__global__ void k_prep0(const float* __restrict__ fv, const float* __restrict__ gt,
                        const float* __restrict__ att_w_ih, const float* __restrict__ dense_w,
                        char* __restrict__ ws){
  int* cnt = (int*)(ws + OFF_CNT);
  float* h1a   = (float*)(ws + OFF_H1A);
  float* h2    = (float*)(ws + OFF_H2);
  float* vmean = (float*)(ws + OFF_VMEAN);
  unsigned short* gtbf = (unsigned short*)(ws + OFF_GTBF);
  unsigned short* wmid = (unsigned short*)(ws + OFF_WMIDBF);
  unsigned short* wd   = (unsigned short*)(ws + OFF_WDBF);
  long gid = (long)blockIdx.x * blockDim.x + threadIdx.x;
  long stride = (long)gridDim.x * blockDim.x;
  if (gid == 0) *cnt = 0;
  for (long i = gid; i < 65536; i += stride){
    if (i < 32768) h1a[i] = 0.f; else h2[i - 32768] = 0.f;
  }
  for (long i = gid; i < 10240000; i += stride) wd[i] = f2bf(dense_w[i]);
  for (long i = gid; i < 688128; i += stride) gtbf[i] = f2bf(gt[i]);
  for (long i = gid; i < 786432; i += stride){
    long j = i >> 9, k = i & 511;
    wmid[i] = f2bf(att_w_ih[j*2048 + 512 + k]);
  }
  for (long i = gid; i < 65536; i += stride){
    long b = i >> 10, f = i & 1023;
    float s = 0.f;
    for (int l = 0; l < 36; ++l) s += fv[b*36864 + l*1024 + f];
    vmean[i] = s * (1.f/36.f);
  }
}

// ---------------- prep1: VMW = b_ih + v_mean@Wright^T ; v_w = fv@fc1^T + b ----------------
__global__ void k_prep1(const float* __restrict__ fv,
                        const float* __restrict__ att_w_ih, const float* __restrict__ att_b_ih,
                        const float* __restrict__ fc1_w, const float* __restrict__ fc1_b,
                        char* __restrict__ ws){
  const float* vmean = (const float*)(ws + OFF_VMEAN);
  float* vmw = (float*)(ws + OFF_VMW);
  float* vwp = (float*)(ws + OFF_VW);
  long gid = (long)blockIdx.x * blockDim.x + threadIdx.x;
  if (gid < 98304){
    long b = gid / 1536, j = gid % 1536;
    const float4* x = (const float4*)(vmean + b*1024);
    const float4* w = (const float4*)(att_w_ih + j*2048 + 1024);
    float s = att_b_ih[j];
    #pragma unroll 8
    for (int k = 0; k < 256; ++k){
      float4 a = x[k], c = w[k];
      s += a.x*c.x + a.y*c.y + a.z*c.z + a.w*c.w;
    }
    vmw[gid] = s;
  } else {
    long i = gid - 98304;              // < 294912
    long bl = i >> 7;                  // b*36 + l
    long c  = i & 127;
    const float4* x = (const float4*)(fv + bl*1024);
    const float4* w = (const float4*)(fc1_w + c*1024);
    float s = fc1_b[c];
    #pragma unroll 8
    for (int k = 0; k < 256; ++k){
      float4 a = x[k], ww = w[k];
      s += a.x*ww.x + a.y*ww.y + a.z*ww.z + a.w*ww.w;
    }
    vwp[i] = s;
  }
}

// ---------------- bf16 MFMA GEMM, K fixed = 512: C[M,N] = A[M,512] @ W[N,512]^T (+bias) ----
// block = 256 thr (4 waves), tile 128(M) x 80(N); global-direct fragment loads.
__global__ __launch_bounds__(256) void k_gemm_bf16(
    const unsigned short* __restrict__ A, const unsigned short* __restrict__ W,
    const float* __restrict__ bias, float* __restrict__ C, int M, int N){
  const int bn = blockIdx.x * 80;
  const int bm = blockIdx.y * 128;
  const int tid = threadIdx.x;
  const int w  = tid >> 6;
  const int l  = tid & 63;
  const int lr = l & 15, lk = l >> 4;
  f32x4 acc[2][5];
  #pragma unroll
  for (int i = 0; i < 2; ++i)
    #pragma unroll
    for (int j = 0; j < 5; ++j) acc[i][j] = (f32x4){0.f,0.f,0.f,0.f};
  long ar[2], wr[5];
  #pragma unroll
  for (int mi = 0; mi < 2; ++mi){
    int r = bm + w*32 + mi*16 + lr;
    ar[mi] = (long)min(r, M-1) * 512;
  }
  #pragma unroll
  for (int ni = 0; ni < 5; ++ni){
    int c = bn + ni*16 + lr;
    wr[ni] = (long)min(c, N-1) * 512;
  }
  for (int ks = 0; ks < 16; ++ks){
    int ko = ks*32 + lk*8;
    bf16x8 a0 = *(const bf16x8*)(A + ar[0] + ko);
    bf16x8 a1 = *(const bf16x8*)(A + ar[1] + ko);
    #pragma unroll
    for (int ni = 0; ni < 5; ++ni){
      bf16x8 wb = *(const bf16x8*)(W + wr[ni] + ko);
      acc[0][ni] = __builtin_amdgcn_mfma_f32_16x16x32_bf16(a0, wb, acc[0][ni], 0,0,0);
      acc[1][ni] = __builtin_amdgcn_mfma_f32_16x16x32_bf16(a1, wb, acc[1][ni], 0,0,0);
    }
  }
  #pragma unroll
  for (int mi = 0; mi < 2; ++mi){
    int row0 = bm + w*32 + mi*16 + lk*4;
    #pragma unroll
    for (int ni = 0; ni < 5; ++ni){
      int col = bn + ni*16 + lr;
      if (col < N){
        float bv = bias ? bias[col] : 0.f;
        #pragma unroll
        for (int r2 = 0; r2 < 4; ++r2){
          int row = row0 + r2;
          if (row < M) C[(long)row*N + col] = acc[mi][ni][r2] + bv;
        }
      }
    }
  }
}

// ---------------- persistent recurrence: 20 steps, 3 grid barriers/step ----------------
// grid = 256 blocks x 512 threads (1 block/CU, co-resident).
// thread mapping for K-parallel dots: tid = b*8 + q  (b=0..63, q=0..7 -> shfl_xor 1,2,4)
__global__ __launch_bounds__(512) void k_recur(
    const float* __restrict__ fv,
    const float* __restrict__ att_w_ih, const float* __restrict__ att_w_hh,
    const float* __restrict__ att_b_hh,
    const float* __restrict__ lang_w_ih, const float* __restrict__ lang_w_hh,
    const float* __restrict__ lang_b_ih, const float* __restrict__ lang_b_hh,
    const float* __restrict__ fc2_w, const float* __restrict__ fc2_b,
    const float* __restrict__ fc3_w, const float* __restrict__ fc3_b,
    char* __restrict__ ws){
  int* cnt = (int*)(ws + OFF_CNT);
  float* h1bufA = (float*)(ws + OFF_H1A);
  float* h1bufB = (float*)(ws + OFF_H1B);
  float* h2  = (float*)(ws + OFF_H2);
  float* mix = (float*)(ws + OFF_MIX);
  const float* vmw  = (const float*)(ws + OFF_VMW);
  const float* vw   = (const float*)(ws + OFF_VW);
  float* G2   = (float*)(ws + OFF_G2);
  float* GHH2 = (float*)(ws + OFF_GHH2);
  const float* prex = (const float*)(ws + OFF_PREX);
  unsigned short* h2bf = (unsigned short*)(ws + OFF_H2BF);

  const int blk = blockIdx.x;
  const int tid = threadIdx.x;
  const int q = tid & 7, b = tid >> 3;

  __shared__ float giS[12][64];
  __shared__ float ghS[12][64];
  __shared__ float hw[128];
  __shared__ float sL[40];
  __shared__ float eL[40];
  __shared__ float sInvS;

  int gen = 0;

  for (int t = 0; t < 20; ++t){
    const float* h1cur = (t & 1) ? h1bufB : h1bufA;
    float*       h1nxt = (t & 1) ? h1bufA : h1bufB;

    // ================= PHASE A =================
    if (blk < 128){
      // att-GRU: cols J = blk*4 .. +3 ; local row r = g*4+c -> W row g*512+blk*4+c
      float4 x2[16], x1[16];
      {
        const float4* p2 = (const float4*)(h2    + b*512 + q*64);
        const float4* p1 = (const float4*)(h1cur + b*512 + q*64);
        #pragma unroll
        for (int i = 0; i < 16; ++i){ x2[i] = p2[i]; x1[i] = p1[i]; }
      }
      float ai[12], ah[12];
      #pragma unroll
      for (int r = 0; r < 12; ++r){ ai[r] = 0.f; ah[r] = 0.f; }
      #pragma unroll
      for (int i = 0; i < 16; ++i){
        float4 a2 = x2[i], a1 = x1[i];
        #pragma unroll
        for (int r = 0; r < 12; ++r){
          int row = (r >> 2)*512 + blk*4 + (r & 3);
          float4 wi = *(const float4*)(att_w_ih + (long)row*2048 + q*64 + i*4);
          float4 wh = *(const float4*)(att_w_hh + (long)row*512  + q*64 + i*4);
          ai[r] += a2.x*wi.x + a2.y*wi.y + a2.z*wi.z + a2.w*wi.w;
          ah[r] += a1.x*wh.x + a1.y*wh.y + a1.z*wh.z + a1.w*wh.w;
        }
      }
      #pragma unroll
      for (int r = 0; r < 12; ++r){
        float vi = ai[r], vh = ah[r];
        vi += __shfl_xor(vi,1); vi += __shfl_xor(vi,2); vi += __shfl_xor(vi,4);
        vh += __shfl_xor(vh,1); vh += __shfl_xor(vh,2); vh += __shfl_xor(vh,4);
        if (q == 0){
          int row = (r >> 2)*512 + blk*4 + (r & 3);
          giS[r][b] = vi;
          ghS[r][b] = vh + att_b_hh[row];
        }
      }
      __syncthreads();
      if (tid < 256){
        int bb = tid & 63, c = tid >> 6;
        int col = blk*4 + c;
        long pb = ((long)bb*21 + t)*1536;
        float ir  = giS[c][bb]   + prex[pb + col]        + vmw[bb*1536 + col];
        float iz  = giS[4+c][bb] + prex[pb + 512 + col]  + vmw[bb*1536 + 512 + col];
        float in_ = giS[8+c][bb] + prex[pb + 1024 + col] + vmw[bb*1536 + 1024 + col];
        float hr = ghS[c][bb], hz = ghS[4+c][bb], hn = ghS[8+c][bb];
        float rg = sigm(ir + hr);
        float zg = sigm(iz + hz);
        float ng = tanhf(in_ + rg*hn);
        h1nxt[bb*512 + col] = (1.f - zg)*ng + zg*h1cur[bb*512 + col];
      }
    } else {
      // GHH2 = b_lang_hh + h2 @ lang_w_hh^T : rows (blk-128)*12 .. +11
      int base = (blk - 128)*12;
      float4 x2[16];
      const float4* p2 = (const float4*)(h2 + b*512 + q*64);
      #pragma unroll
      for (int i = 0; i < 16; ++i) x2[i] = p2[i];
      float ac[12];
      #pragma unroll
      for (int r = 0; r < 12; ++r) ac[r] = 0.f;
      #pragma unroll
      for (int i = 0; i < 16; ++i){
        float4 a2 = x2[i];
        #pragma unroll
        for (int r = 0; r < 12; ++r){
          float4 wh = *(const float4*)(lang_w_hh + (long)(base + r)*512 + q*64 + i*4);
          ac[r] += a2.x*wh.x + a2.y*wh.y + a2.z*wh.z + a2.w*wh.w;
        }
      }
      #pragma unroll
      for (int r = 0; r < 12; ++r){
        float v = ac[r];
        v += __shfl_xor(v,1); v += __shfl_xor(v,2); v += __shfl_xor(v,4);
        if (q == 0) GHH2[(long)(base + r)*64 + b] = v + lang_b_hh[base + r];
      }
    }
    gbar(cnt, 256*(++gen));

    // ================= PHASE B =================
    if (blk < 64){
      const int bb = blk;
      { // h_w = h1_new @ fc2^T + b : c = tid>>2, qq = tid&3 (K-slice 128)
        int c = tid >> 2, qq = tid & 3;
        const float4* x = (const float4*)(h1nxt + bb*512 + qq*128);
        const float4* w = (const float4*)(fc2_w + (long)c*512 + qq*128);
        float s = 0.f;
        #pragma unroll 8
        for (int i = 0; i < 32; ++i){
          float4 a = x[i], ww = w[i];
          s += a.x*ww.x + a.y*ww.y + a.z*ww.z + a.w*ww.w;
        }
        s += __shfl_xor(s,1); s += __shfl_xor(s,2);
        if (qq == 0) hw[c] = s + fc2_b[c];
      }
      __syncthreads();
      if (tid < 288){ // s[l]: l = tid>>3, j = tid&7, c-slice 16
        int ll = tid >> 3, j = tid & 7;
        float s = 0.f;
        const float* vrow = vw + (long)bb*4608 + ll*128;
        #pragma unroll
        for (int k = 0; k < 16; ++k){
          int cc = j*16 + k;
          s += tanhf(vrow[cc] + hw[cc]) * fc3_w[cc];
        }
        s += __shfl_xor(s,1); s += __shfl_xor(s,2); s += __shfl_xor(s,4);
        if (j == 0) sL[ll] = s + fc3_b[0];
      }
      __syncthreads();
      if (tid == 0){
        float m = -1e30f;
        for (int ll = 0; ll < 36; ++ll) m = fmaxf(m, sL[ll]);
        float ssum = 0.f;
        for (int ll = 0; ll < 36; ++ll){ float e = __expf(sL[ll] - m); eL[ll] = e; ssum += e; }
        sInvS = 1.f / ssum;
      }
      __syncthreads();
      float sInv = sInvS;
      for (int f = tid; f < 1024; f += 512){
        float mv = 0.f;
        #pragma unroll
        for (int ll = 0; ll < 36; ++ll) mv += eL[ll] * fv[(long)bb*36864 + ll*1024 + f];
        mix[bb*1024 + f] = mv * sInv;
      }
    } else {
      // G2 = b_lang_ih + h1_new @ lwB^T (lang_w_ih cols 1024..1535): rows (blk-64)*8 .. +7
      int base = (blk - 64)*8;
      float4 x1[16];
      const float4* p1 = (const float4*)(h1nxt + b*512 + q*64);
      #pragma unroll
      for (int i = 0; i < 16; ++i) x1[i] = p1[i];
      float ac[8];
      #pragma unroll
      for (int r = 0; r < 8; ++r) ac[r] = 0.f;
      #pragma unroll
      for (int i = 0; i < 16; ++i){
        float4 a1 = x1[i];
        #pragma unroll
        for (int r = 0; r < 8; ++r){
          float4 w = *(const float4*)(lang_w_ih + (long)(base + r)*1536 + 1024 + q*64 + i*4);
          ac[r] += a1.x*w.x + a1.y*w.y + a1.z*w.z + a1.w*w.w;
        }
      }
      #pragma unroll
      for (int r = 0; r < 8; ++r){
        float v = ac[r];
        v += __shfl_xor(v,1); v += __shfl_xor(v,2); v += __shfl_xor(v,4);
        if (q == 0) G2[(long)(base + r)*64 + b] = v + lang_b_ih[base + r];
      }
    }
    gbar(cnt, 256*(++gen));

    // ================= PHASE C =================
    if (blk < 128){
      // lang-GRU mix-part: cols J = blk*4..+3, K=1024 over mix
      float4 mx[32];
      const float4* pm = (const float4*)(mix + b*1024 + q*128);
      #pragma unroll
      for (int i = 0; i < 32; ++i) mx[i] = pm[i];
      float ac[12];
      #pragma unroll
      for (int r = 0; r < 12; ++r) ac[r] = 0.f;
      #pragma unroll
      for (int i = 0; i < 32; ++i){
        float4 a = mx[i];
        #pragma unroll
        for (int r = 0; r < 12; ++r){
          int row = (r >> 2)*512 + blk*4 + (r & 3);
          float4 w = *(const float4*)(lang_w_ih + (long)row*1536 + q*128 + i*4);
          ac[r] += a.x*w.x + a.y*w.y + a.z*w.z + a.w*w.w;
        }
      }
      #pragma unroll
      for (int r = 0; r < 12; ++r){
        float v = ac[r];
        v += __shfl_xor(v,1); v += __shfl_xor(v,2); v += __shfl_xor(v,4);
        if (q == 0) giS[r][b] = v;
      }
      __syncthreads();
      if (tid < 256){
        int bb = tid & 63, c = tid >> 6;
        int col = blk*4 + c;
        float gir = giS[c][bb]   + G2[(long)(col)*64 + bb];
        float giz = giS[4+c][bb] + G2[(long)(512 + col)*64 + bb];
        float gin = giS[8+c][bb] + G2[(long)(1024 + col)*64 + bb];
        float ghr = GHH2[(long)(col)*64 + bb];
        float ghz = GHH2[(long)(512 + col)*64 + bb];
        float ghn = GHH2[(long)(1024 + col)*64 + bb];
        float rg = sigm(gir + ghr);
        float zg = sigm(giz + ghz);
        float ng = tanhf(gin + rg*ghn);
        float hv = (1.f - zg)*ng + zg*h2[bb*512 + col];
        h2[bb*512 + col] = hv;
        h2bf[((long)bb*20 + t)*512 + col] = f2bf(hv);
      }
    }
    if (t < 19) gbar(cnt, 256*(++gen));
  }
}

// ---------------- host launch ----------------
extern "C" void kernel_launch(void* const* d_in, const int* in_sizes, int n_in,
                              void* d_out, int out_size, void* d_ws, size_t ws_size,
                              hipStream_t stream){
  const float* fv   = (const float*)d_in[0];
  const float* gt   = (const float*)d_in[2];
  const float* awih = (const float*)d_in[3];
  const float* awhh = (const float*)d_in[4];
  const float* abih = (const float*)d_in[5];
  const float* abhh = (const float*)d_in[6];
  const float* lwih = (const float*)d_in[7];
  const float* lwhh = (const float*)d_in[8];
  const float* lbih = (const float*)d_in[9];
  const float* lbhh = (const float*)d_in[10];
  const float* fc1w = (const float*)d_in[11];
  const float* fc1b = (const float*)d_in[12];
  const float* fc2w = (const float*)d_in[13];
  const float* fc2b = (const float*)d_in[14];
  const float* fc3w = (const float*)d_in[15];
  const float* fc3b = (const float*)d_in[16];
  const float* dw   = (const float*)d_in[17];
  const float* db   = (const float*)d_in[18];
  char* ws = (char*)d_ws;
  float* out = (float*)d_out;

  // prep: zero states/counter, bf16 conversions, v_mean
  k_prep0<<<dim3(2048), dim3(256), 0, stream>>>(fv, gt, awih, dw, ws);
  // VMW + v_w (one thread per output, exact thread count)
  k_prep1<<<dim3(1536), dim3(256), 0, stream>>>(fv, awih, abih, fc1w, fc1b, ws);
  // PREx[b*21+t][1536] = x_t @ Wmid^T  (MFMA bf16)
  k_gemm_bf16<<<dim3(20, 11), dim3(256), 0, stream>>>(
      (const unsigned short*)(ws + OFF_GTBF), (const unsigned short*)(ws + OFF_WMIDBF),
      (const float*)nullptr, (float*)(ws + OFF_PREX), 1344, 1536);
  // 20-step recurrence (persistent, 256 blocks co-resident)
  k_recur<<<dim3(256), dim3(512), 0, stream>>>(
      fv, awih, awhh, abhh, lwih, lwhh, lbih, lbhh, fc2w, fc2b, fc3w, fc3b, ws);
  // logits = H2 @ dense_w^T + dense_b  (MFMA bf16, M=1280 N=20000 K=512)
  k_gemm_bf16<<<dim3(250, 10), dim3(256), 0, stream>>>(
      (const unsigned short*)(ws + OFF_H2BF), (const unsigned short*)(ws + OFF_WDBF),
      db, out, 1280, 20000);
}

// Round 2
// 2687.141 us; speedup vs baseline: 6.5264x; 6.5264x over previous
//
#include <hip/hip_runtime.h>
#include <hip/hip_bf16.h>
#include <math.h>

// B=64, steps=20 (T=21), L=36, E=512, H=512, F=1024, VOC=20000
// att_in=2048 (h2|x_t|v_mean), lang_in=1536 (mix|h1), 3H=1536
// 4 batch-groups x 16 items; all gate GEMMs are M=16 MFMA with bf16 hi/lo split.

typedef __attribute__((ext_vector_type(8))) short bf16x8;
typedef __attribute__((ext_vector_type(4))) float f32x4;
typedef unsigned short u16;
typedef unsigned int u32;

#define MFMA16 __builtin_amdgcn_mfma_f32_16x16x32_bf16

__device__ __forceinline__ u16 f2bf(float f){
  u32 u = __float_as_uint(f);
  u += 0x7fffu + ((u >> 16) & 1u);
  return (u16)(u >> 16);
}
__device__ __forceinline__ float bf2f(u16 u){ return __uint_as_float(((u32)u) << 16); }
__device__ __forceinline__ float sigm(float x){ return 1.0f/(1.0f+__expf(-x)); }

// ---------------- workspace layout (bytes) ----------------
#define OFF_VMEAN  ((size_t)0)           // 64*1024 f32          = 262144
#define OFF_VMW    ((size_t)262144)      // 64*1536 f32          = 393216
#define OFF_VW     ((size_t)655360)      // 64*36*128 f32        = 1179648
#define OFF_PREX   ((size_t)1835008)     // 1344*1536 f32        = 8257536
#define OFF_GTBF   ((size_t)10092544)    // 1344*512 bf16        = 1376256
#define OFF_WMIDBF ((size_t)11468800)    // 1536*512 bf16        = 1572864
#define OFF_WIH2HI ((size_t)13041664)    // 1536*512 bf16
#define OFF_WIH2LO ((size_t)14614528)
#define OFF_AWHHHI ((size_t)16187392)
#define OFF_AWHHLO ((size_t)17760256)
#define OFF_LWHHHI ((size_t)19333120)
#define OFF_LWHHLO ((size_t)20905984)
#define OFF_LWIHHI ((size_t)22478848)    // 1536*1536 bf16 = 4718592
#define OFF_LWIHLO ((size_t)27197440)
#define OFF_H1HI   ((size_t)31916032)    // 2*64*512 u16 = 131072 (parity-double-buffered)
#define OFF_H1LO   ((size_t)32047104)
#define OFF_H2HI   ((size_t)32178176)
#define OFF_H2LO   ((size_t)32309248)
#define OFF_MIXHI  ((size_t)32440320)    // 64*1024 u16 = 131072
#define OFF_MIXLO  ((size_t)32571392)
#define OFF_G2F    ((size_t)32702464)    // 64*1536 f32 = 393216 (b_lang_ih + h1new@lwih[:,1024:]^T)
#define OFF_GHH2F  ((size_t)33095680)    // 64*1536 f32 (b_lang_hh + h2@lwhh^T)
#define OFF_H2BF   ((size_t)33488896)    // 1280*512 bf16 = 1310720
// total 34,799,616 B (< round-1's proven 36.1MB)

// ---------------- prep0: zeros, bf16 + hi/lo conversions, v_mean ----------------
__global__ __launch_bounds__(256) void k_prep0(
    const float* __restrict__ fv, const float* __restrict__ gt,
    const float* __restrict__ awih, const float* __restrict__ awhh,
    const float* __restrict__ lwih, const float* __restrict__ lwhh,
    char* __restrict__ ws){
  long gid = (long)blockIdx.x * blockDim.x + threadIdx.x;
  long stride = (long)gridDim.x * blockDim.x;
  u32* zh1h = (u32*)(ws + OFF_H1HI);
  u32* zh1l = (u32*)(ws + OFF_H1LO);
  u32* zh2h = (u32*)(ws + OFF_H2HI);
  u32* zh2l = (u32*)(ws + OFF_H2LO);
  for (long i = gid; i < 16384; i += stride){ zh1h[i]=0; zh1l[i]=0; zh2h[i]=0; zh2l[i]=0; }
  u16* gtbf = (u16*)(ws + OFF_GTBF);
  for (long i = gid; i < 688128; i += stride) gtbf[i] = f2bf(gt[i]);
  u16* wmid = (u16*)(ws + OFF_WMIDBF);
  for (long i = gid; i < 786432; i += stride)
    wmid[i] = f2bf(awih[(i>>9)*2048 + 512 + (i&511)]);
  u16* w2h = (u16*)(ws + OFF_WIH2HI); u16* w2l = (u16*)(ws + OFF_WIH2LO);
  for (long i = gid; i < 786432; i += stride){
    float x = awih[(i>>9)*2048 + (i&511)];
    u16 h = f2bf(x); w2h[i] = h; w2l[i] = f2bf(x - bf2f(h));
  }
  u16* ahh = (u16*)(ws + OFF_AWHHHI); u16* ahl = (u16*)(ws + OFF_AWHHLO);
  for (long i = gid; i < 786432; i += stride){
    float x = awhh[i]; u16 h = f2bf(x); ahh[i] = h; ahl[i] = f2bf(x - bf2f(h));
  }
  u16* lhh = (u16*)(ws + OFF_LWHHHI); u16* lhl = (u16*)(ws + OFF_LWHHLO);
  for (long i = gid; i < 786432; i += stride){
    float x = lwhh[i]; u16 h = f2bf(x); lhh[i] = h; lhl[i] = f2bf(x - bf2f(h));
  }
  u16* lih = (u16*)(ws + OFF_LWIHHI); u16* lil = (u16*)(ws + OFF_LWIHLO);
  for (long i = gid; i < 2359296; i += stride){
    float x = lwih[i]; u16 h = f2bf(x); lih[i] = h; lil[i] = f2bf(x - bf2f(h));
  }
  float* vmean = (float*)(ws + OFF_VMEAN);
  for (long i = gid; i < 65536; i += stride){
    long b = i >> 10, f = i & 1023;
    float s = 0.f;
    for (int l = 0; l < 36; ++l) s += fv[b*36864 + l*1024 + f];
    vmean[i] = s * (1.f/36.f);
  }
}

// ---------------- prep1: VMW = b_ih + v_mean@Wright^T ; v_w = fv@fc1^T + b ----------------
__global__ __launch_bounds__(256) void k_prep1(const float* __restrict__ fv,
    const float* __restrict__ att_w_ih, const float* __restrict__ att_b_ih,
    const float* __restrict__ fc1_w, const float* __restrict__ fc1_b,
    char* __restrict__ ws){
  const float* vmean = (const float*)(ws + OFF_VMEAN);
  float* vmw = (float*)(ws + OFF_VMW);
  float* vwp = (float*)(ws + OFF_VW);
  long gid = (long)blockIdx.x * blockDim.x + threadIdx.x;
  if (gid < 98304){
    long b = gid / 1536, j = gid % 1536;
    const float4* x = (const float4*)(vmean + b*1024);
    const float4* w = (const float4*)(att_w_ih + j*2048 + 1024);
    float s = att_b_ih[j];
    #pragma unroll 8
    for (int k = 0; k < 256; ++k){
      float4 a = x[k], c = w[k];
      s += a.x*c.x + a.y*c.y + a.z*c.z + a.w*c.w;
    }
    vmw[gid] = s;
  } else {
    long i = gid - 98304;              // < 294912
    long bl = i >> 7, c = i & 127;
    const float4* x = (const float4*)(fv + bl*1024);
    const float4* w = (const float4*)(fc1_w + c*1024);
    float s = fc1_b[c];
    #pragma unroll 8
    for (int k = 0; k < 256; ++k){
      float4 a = x[k], ww = w[k];
      s += a.x*ww.x + a.y*ww.y + a.z*ww.z + a.w*ww.w;
    }
    vwp[i] = s;
  }
}

// ---------------- bf16 MFMA GEMM (pre-converted operands), K=512 ----------------
__global__ __launch_bounds__(256) void k_gemm_bf16(
    const u16* __restrict__ A, const u16* __restrict__ W,
    const float* __restrict__ bias, float* __restrict__ C, int M, int N){
  const int bn = blockIdx.x * 80, bm = blockIdx.y * 128;
  const int tid = threadIdx.x, w = tid >> 6, l = tid & 63;
  const int lr = l & 15, lk = l >> 4;
  f32x4 acc[2][5];
  #pragma unroll
  for (int i = 0; i < 2; ++i)
    #pragma unroll
    for (int j = 0; j < 5; ++j) acc[i][j] = (f32x4){0.f,0.f,0.f,0.f};
  long ar[2], wr[5];
  #pragma unroll
  for (int mi = 0; mi < 2; ++mi) ar[mi] = (long)min(bm + w*32 + mi*16 + lr, M-1) * 512;
  #pragma unroll
  for (int ni = 0; ni < 5; ++ni) wr[ni] = (long)min(bn + ni*16 + lr, N-1) * 512;
  for (int ks = 0; ks < 16; ++ks){
    int ko = ks*32 + lk*8;
    bf16x8 a0 = *(const bf16x8*)(A + ar[0] + ko);
    bf16x8 a1 = *(const bf16x8*)(A + ar[1] + ko);
    #pragma unroll
    for (int ni = 0; ni < 5; ++ni){
      bf16x8 wb = *(const bf16x8*)(W + wr[ni] + ko);
      acc[0][ni] = MFMA16(a0, wb, acc[0][ni], 0,0,0);
      acc[1][ni] = MFMA16(a1, wb, acc[1][ni], 0,0,0);
    }
  }
  #pragma unroll
  for (int mi = 0; mi < 2; ++mi){
    int row0 = bm + w*32 + mi*16 + lk*4;
    #pragma unroll
    for (int ni = 0; ni < 5; ++ni){
      int col = bn + ni*16 + lr;
      if (col < N){
        float bv = bias ? bias[col] : 0.f;
        #pragma unroll
        for (int r2 = 0; r2 < 4; ++r2){
          int row = row0 + r2;
          if (row < M) C[(long)row*N + col] = acc[mi][ni][r2] + bv;
        }
      }
    }
  }
}

// ---------------- vocab GEMM: A bf16, W fp32 converted on the fly ----------------
__device__ __forceinline__ bf16x8 cvt8(float4 a, float4 b){
  union { bf16x8 v; u32 u[4]; } r;
  asm("v_cvt_pk_bf16_f32 %0, %1, %2" : "=v"(r.u[0]) : "v"(a.x), "v"(a.y));
  asm("v_cvt_pk_bf16_f32 %0, %1, %2" : "=v"(r.u[1]) : "v"(a.z), "v"(a.w));
  asm("v_cvt_pk_bf16_f32 %0, %1, %2" : "=v"(r.u[2]) : "v"(b.x), "v"(b.y));
  asm("v_cvt_pk_bf16_f32 %0, %1, %2" : "=v"(r.u[3]) : "v"(b.z), "v"(b.w));
  return r.v;
}
__global__ __launch_bounds__(256) void k_gemm_vocab(
    const u16* __restrict__ A, const float* __restrict__ W,
    const float* __restrict__ bias, float* __restrict__ C, int M, int N){
  const int bn = blockIdx.x * 80, bm = blockIdx.y * 128;
  const int tid = threadIdx.x, w = tid >> 6, l = tid & 63;
  const int lr = l & 15, lk = l >> 4;
  f32x4 acc[2][5];
  #pragma unroll
  for (int i = 0; i < 2; ++i)
    #pragma unroll
    for (int j = 0; j < 5; ++j) acc[i][j] = (f32x4){0.f,0.f,0.f,0.f};
  long ar[2], wr[5];
  #pragma unroll
  for (int mi = 0; mi < 2; ++mi) ar[mi] = (long)min(bm + w*32 + mi*16 + lr, M-1) * 512;
  #pragma unroll
  for (int ni = 0; ni < 5; ++ni) wr[ni] = (long)min(bn + ni*16 + lr, N-1) * 512;
  for (int ks = 0; ks < 16; ++ks){
    int ko = ks*32 + lk*8;
    bf16x8 a0 = *(const bf16x8*)(A + ar[0] + ko);
    bf16x8 a1 = *(const bf16x8*)(A + ar[1] + ko);
    #pragma unroll
    for (int ni = 0; ni < 5; ++ni){
      float4 w0 = *(const float4*)(W + wr[ni] + ko);
      float4 w1 = *(const float4*)(W + wr[ni] + ko + 4);
      bf16x8 wb = cvt8(w0, w1);
      acc[0][ni] = MFMA16(a0, wb, acc[0][ni], 0,0,0);
      acc[1][ni] = MFMA16(a1, wb, acc[1][ni], 0,0,0);
    }
  }
  #pragma unroll
  for (int mi = 0; mi < 2; ++mi){
    int row0 = bm + w*32 + mi*16 + lk*4;
    #pragma unroll
    for (int ni = 0; ni < 5; ++ni){
      int col = bn + ni*16 + lr;
      if (col < N){
        float bv = bias[col];
        #pragma unroll
        for (int r2 = 0; r2 < 4; ++r2){
          int row = row0 + r2;
          if (row < M) C[(long)row*N + col] = acc[mi][ni][r2] + bv;
        }
      }
    }
  }
}

// ---------------- phase A: att-GRU (gates + fused combine) || GHH2 ----------------
// grid 48 x 256thr. blk<32: att (g=blk>>3, 64 cols each, wave=16-col set, 6 tiles + combine)
//                    blk>=32: GHH2 (g=(blk-32)>>2, 384 rows each, wave=96 rows = 6 tiles)
__global__ __launch_bounds__(256) void k_phaseA(char* __restrict__ ws,
    const float* __restrict__ abhh, const float* __restrict__ lbhh, int t, int pa){
  const int blk = blockIdx.x, tid = threadIdx.x;
  const int wid = tid >> 6, lane = tid & 63, lr = lane & 15, lk = lane >> 4;
  const int pn = pa ^ 1;
  const u16* h2hi = (const u16*)(ws + OFF_H2HI) + pa*32768;
  const u16* h2lo = (const u16*)(ws + OFF_H2LO) + pa*32768;
  if (blk < 32){
    const int g = blk >> 3;
    const int j0 = (blk & 7)*64 + wid*16;
    const u16* h1hi = (const u16*)(ws + OFF_H1HI) + pa*32768;
    const u16* h1lo = (const u16*)(ws + OFF_H1LO) + pa*32768;
    u16* h1hiN = (u16*)(ws + OFF_H1HI) + pn*32768;
    u16* h1loN = (u16*)(ws + OFF_H1LO) + pn*32768;
    const u16* wIh = (const u16*)(ws + OFF_WIH2HI);
    const u16* wIl = (const u16*)(ws + OFF_WIH2LO);
    const u16* wHh = (const u16*)(ws + OFF_AWHHHI);
    const u16* wHl = (const u16*)(ws + OFF_AWHHLO);
    const float* prex = (const float*)(ws + OFF_PREX);
    const float* vmw  = (const float*)(ws + OFF_VMW);
    const int bA = g*16 + lr;
    const u16* pA2h = h2hi + bA*512; const u16* pA2l = h2lo + bA*512;
    const u16* pA1h = h1hi + bA*512; const u16* pA1l = h1lo + bA*512;
    const u16 *pWI[3], *pWIl[3], *pWH[3], *pWHl[3];
    #pragma unroll
    for (int gt_ = 0; gt_ < 3; ++gt_){
      int r = gt_*512 + j0 + lr;
      pWI[gt_]  = wIh + r*512; pWIl[gt_] = wIl + r*512;
      pWH[gt_]  = wHh + r*512; pWHl[gt_] = wHl + r*512;
    }
    f32x4 accI[3], accH[3];
    #pragma unroll
    for (int i = 0; i < 3; ++i){ accI[i] = (f32x4){0,0,0,0}; accH[i] = (f32x4){0,0,0,0}; }
    for (int ks = 0; ks < 16; ++ks){
      const int ko = ks*32 + lk*8;
      bf16x8 a2h = *(const bf16x8*)(pA2h + ko);
      bf16x8 a2l = *(const bf16x8*)(pA2l + ko);
      bf16x8 a1h = *(const bf16x8*)(pA1h + ko);
      bf16x8 a1l = *(const bf16x8*)(pA1l + ko);
      #pragma unroll
      for (int gt_ = 0; gt_ < 3; ++gt_){
        bf16x8 wh = *(const bf16x8*)(pWI[gt_] + ko);
        bf16x8 wl = *(const bf16x8*)(pWIl[gt_] + ko);
        accI[gt_] = MFMA16(a2h, wh, accI[gt_], 0,0,0);
        accI[gt_] = MFMA16(a2l, wh, accI[gt_], 0,0,0);
        accI[gt_] = MFMA16(a2h, wl, accI[gt_], 0,0,0);
        bf16x8 vh = *(const bf16x8*)(pWH[gt_] + ko);
        bf16x8 vl = *(const bf16x8*)(pWHl[gt_] + ko);
        accH[gt_] = MFMA16(a1h, vh, accH[gt_], 0,0,0);
        accH[gt_] = MFMA16(a1l, vh, accH[gt_], 0,0,0);
        accH[gt_] = MFMA16(a1h, vl, accH[gt_], 0,0,0);
      }
    }
    // fused GRU combine: lane holds (col c = j0+lr, items m = lk*4+reg)
    const int c = j0 + lr;
    const float bhr = abhh[c], bhz = abhh[512+c], bhn = abhh[1024+c];
    #pragma unroll
    for (int reg = 0; reg < 4; ++reg){
      int b = g*16 + lk*4 + reg;
      long pb = ((long)b*21 + t)*1536;
      float ir  = accI[0][reg] + prex[pb + c]        + vmw[b*1536 + c];
      float iz  = accI[1][reg] + prex[pb + 512 + c]  + vmw[b*1536 + 512 + c];
      float in_ = accI[2][reg] + prex[pb + 1024 + c] + vmw[b*1536 + 1024 + c];
      float hr = accH[0][reg] + bhr;
      float hz = accH[1][reg] + bhz;
      float hn = accH[2][reg] + bhn;
      float r_ = sigm(ir + hr);
      float z_ = sigm(iz + hz);
      float n_ = tanhf(in_ + r_*hn);
      float hold = bf2f(h1hi[b*512 + c]) + bf2f(h1lo[b*512 + c]);
      float hv = (1.f - z_)*n_ + z_*hold;
      u16 hh = f2bf(hv);
      h1hiN[b*512 + c] = hh;
      h1loN[b*512 + c] = f2bf(hv - bf2f(hh));
    }
  } else {
    const int blk2 = blk - 32;
    const int g = blk2 >> 2;
    const int rb0 = (blk2 & 3)*384 + wid*96;
    const u16* wh_ = (const u16*)(ws + OFF_LWHHHI);
    const u16* wl_ = (const u16*)(ws + OFF_LWHHLO);
    float* GHH2F = (float*)(ws + OFF_GHH2F);
    const int bA = g*16 + lr;
    const u16* pAh = h2hi + bA*512; const u16* pAl = h2lo + bA*512;
    f32x4 acc[6];
    #pragma unroll
    for (int i = 0; i < 6; ++i) acc[i] = (f32x4){0,0,0,0};
    const u16 *pW[6], *pWl[6];
    #pragma unroll
    for (int tl = 0; tl < 6; ++tl){
      int r = rb0 + tl*16 + lr;
      pW[tl] = wh_ + r*512; pWl[tl] = wl_ + r*512;
    }
    for (int ks = 0; ks < 16; ++ks){
      const int ko = ks*32 + lk*8;
      bf16x8 ah = *(const bf16x8*)(pAh + ko);
      bf16x8 al = *(const bf16x8*)(pAl + ko);
      #pragma unroll
      for (int tl = 0; tl < 6; ++tl){
        bf16x8 wh = *(const bf16x8*)(pW[tl] + ko);
        bf16x8 wl = *(const bf16x8*)(pWl[tl] + ko);
        acc[tl] = MFMA16(ah, wh, acc[tl], 0,0,0);
        acc[tl] = MFMA16(al, wh, acc[tl], 0,0,0);
        acc[tl] = MFMA16(ah, wl, acc[tl], 0,0,0);
      }
    }
    #pragma unroll
    for (int tl = 0; tl < 6; ++tl){
      int rr = rb0 + tl*16 + lr;
      float bb = lbhh[rr];
      #pragma unroll
      for (int reg = 0; reg < 4; ++reg){
        int b = g*16 + lk*4 + reg;
        GHH2F[(long)b*1536 + rr] = acc[tl][reg] + bb;
      }
    }
  }
}

// ---------------- phase B: G2 (lang ih h1-part) || attention path ----------------
// grid 80: blk<16 G2 MFMA (g=blk>>2, 384 rows), blk>=16 attention (item b = blk-16)
__global__ __launch_bounds__(256) void k_phaseB(char* __restrict__ ws,
    const float* __restrict__ fv,
    const float* __restrict__ fc2w, const float* __restrict__ fc2b,
    const float* __restrict__ fc3w, const float* __restrict__ lbih, int pa){
  const int blk = blockIdx.x, tid = threadIdx.x;
  const int pn = pa ^ 1;
  const u16* h1hi = (const u16*)(ws + OFF_H1HI) + pn*32768;
  const u16* h1lo = (const u16*)(ws + OFF_H1LO) + pn*32768;
  if (blk < 16){
    const int wid = tid >> 6, lane = tid & 63, lr = lane & 15, lk = lane >> 4;
    const int g = blk >> 2;
    const int rb0 = (blk & 3)*384 + wid*96;
    const u16* wih = (const u16*)(ws + OFF_LWIHHI);
    const u16* wil = (const u16*)(ws + OFF_LWIHLO);
    float* G2F = (float*)(ws + OFF_G2F);
    const int bA = g*16 + lr;
    const u16* pAh = h1hi + bA*512; const u16* pAl = h1lo + bA*512;
    f32x4 acc[6];
    #pragma unroll
    for (int i = 0; i < 6; ++i) acc[i] = (f32x4){0,0,0,0};
    const u16 *pW[6], *pWl[6];
    #pragma unroll
    for (int tl = 0; tl < 6; ++tl){
      int r = rb0 + tl*16 + lr;
      pW[tl] = wih + (long)r*1536 + 1024; pWl[tl] = wil + (long)r*1536 + 1024;
    }
    for (int ks = 0; ks < 16; ++ks){
      const int ko = ks*32 + lk*8;
      bf16x8 ah = *(const bf16x8*)(pAh + ko);
      bf16x8 al = *(const bf16x8*)(pAl + ko);
      #pragma unroll
      for (int tl = 0; tl < 6; ++tl){
        bf16x8 wh = *(const bf16x8*)(pW[tl] + ko);
        bf16x8 wl = *(const bf16x8*)(pWl[tl] + ko);
        acc[tl] = MFMA16(ah, wh, acc[tl], 0,0,0);
        acc[tl] = MFMA16(al, wh, acc[tl], 0,0,0);
        acc[tl] = MFMA16(ah, wl, acc[tl], 0,0,0);
      }
    }
    #pragma unroll
    for (int tl = 0; tl < 6; ++tl){
      int rr = rb0 + tl*16 + lr;
      float bb = lbih[rr];
      #pragma unroll
      for (int reg = 0; reg < 4; ++reg){
        int b = g*16 + lk*4 + reg;
        G2F[(long)b*1536 + rr] = acc[tl][reg] + bb;
      }
    }
  } else {
    const int b = blk - 16;
    const float* vw = (const float*)(ws + OFF_VW);
    u16* mixhi = (u16*)(ws + OFF_MIXHI);
    u16* mixlo = (u16*)(ws + OFF_MIXLO);
    __shared__ float sh1[512];
    __shared__ float hwS[128];
    __shared__ float sS[36];
    __shared__ float aS[36];
    for (int i = tid; i < 512; i += 256)
      sh1[i] = bf2f(h1hi[b*512 + i]) + bf2f(h1lo[b*512 + i]);
    __syncthreads();
    { // hw[128] = h1new @ fc2^T + b
      int c = tid >> 1, hf = tid & 1;
      const float4* x = (const float4*)(sh1 + hf*256);
      const float4* w = (const float4*)(fc2w + c*512 + hf*256);
      float s = 0.f;
      #pragma unroll 8
      for (int i = 0; i < 64; ++i){
        float4 a = x[i], ww = w[i];
        s += a.x*ww.x + a.y*ww.y + a.z*ww.z + a.w*ww.w;
      }
      s += __shfl_xor(s, 1);
      if (hf == 0) hwS[c] = s + fc2b[c];
    }
    __syncthreads();
    { // s[l] = tanh(vw+hw) . fc3
      int j = tid & 15, l0 = tid >> 4;   // l0 in 0..15
      for (int lb = 0; lb < 48; lb += 16){
        int l = lb + l0;
        float s = 0.f;
        if (l < 36){
          const float* vr = vw + (long)b*4608 + l*128;
          #pragma unroll
          for (int k = j*8; k < j*8 + 8; ++k) s += tanhf(vr[k] + hwS[k]) * fc3w[k];
        }
        s += __shfl_xor(s,1); s += __shfl_xor(s,2); s += __shfl_xor(s,4); s += __shfl_xor(s,8);
        if (j == 0 && l < 36) sS[l] = s;
      }
    }
    __syncthreads();
    if (tid == 0){
      float m = -1e30f;
      for (int l = 0; l < 36; ++l) m = fmaxf(m, sS[l]);
      float sum = 0.f;
      for (int l = 0; l < 36; ++l){ float e = __expf(sS[l] - m); aS[l] = e; sum += e; }
      float inv = 1.f / sum;
      for (int l = 0; l < 36; ++l) aS[l] *= inv;
    }
    __syncthreads();
    { // mix[f] = sum_l a[l] * fv[b][l][f], 4 cols per thread
      float4 acc = (float4){0,0,0,0};
      const float* base = fv + (long)b*36864 + tid*4;
      for (int l = 0; l < 36; ++l){
        float a = aS[l];
        float4 v = *(const float4*)(base + l*1024);
        acc.x += a*v.x; acc.y += a*v.y; acc.z += a*v.z; acc.w += a*v.w;
      }
      ushort4 hi4, lo4;
      u16 h;
      h = f2bf(acc.x); hi4.x = h; lo4.x = f2bf(acc.x - bf2f(h));
      h = f2bf(acc.y); hi4.y = h; lo4.y = f2bf(acc.y - bf2f(h));
      h = f2bf(acc.z); hi4.z = h; lo4.z = f2bf(acc.z - bf2f(h));
      h = f2bf(acc.w); hi4.w = h; lo4.w = f2bf(acc.w - bf2f(h));
      *(ushort4*)(mixhi + b*1024 + tid*4) = hi4;
      *(ushort4*)(mixlo + b*1024 + tid*4) = lo4;
    }
  }
}

// ---------------- phase C: lang-GRU mix-part GEMM + fused h2 combine ----------------
// grid 32: g = blk>>3, wave = 16-col set (3 gate tiles, K=1024 over mix)
__global__ __launch_bounds__(256) void k_phaseC(char* __restrict__ ws, int t, int pa){
  const int blk = blockIdx.x, tid = threadIdx.x;
  const int wid = tid >> 6, lane = tid & 63, lr = lane & 15, lk = lane >> 4;
  const int pn = pa ^ 1;
  const int g = blk >> 3;
  const int c0 = (blk & 7)*64 + wid*16;
  const u16* mixhi = (const u16*)(ws + OFF_MIXHI);
  const u16* mixlo = (const u16*)(ws + OFF_MIXLO);
  const u16* wih = (const u16*)(ws + OFF_LWIHHI);
  const u16* wil = (const u16*)(ws + OFF_LWIHLO);
  const float* G2F   = (const float*)(ws + OFF_G2F);
  const float* GHH2F = (const float*)(ws + OFF_GHH2F);
  const u16* h2hiO = (const u16*)(ws + OFF_H2HI) + pa*32768;
  const u16* h2loO = (const u16*)(ws + OFF_H2LO) + pa*32768;
  u16* h2hiN = (u16*)(ws + OFF_H2HI) + pn*32768;
  u16* h2loN = (u16*)(ws + OFF_H2LO) + pn*32768;
  u16* h2bf  = (u16*)(ws + OFF_H2BF);
  const int bA = g*16 + lr;
  const u16* pAh = mixhi + bA*1024; const u16* pAl = mixlo + bA*1024;
  const u16 *pW[3], *pWl[3];
  #pragma unroll
  for (int gt_ = 0; gt_ < 3; ++gt_){
    int r = gt_*512 + c0 + lr;
    pW[gt_] = wih + (long)r*1536; pWl[gt_] = wil + (long)r*1536;
  }
  f32x4 acc[3];
  #pragma unroll
  for (int i = 0; i < 3; ++i) acc[i] = (f32x4){0,0,0,0};
  for (int ks = 0; ks < 32; ++ks){
    const int ko = ks*32 + lk*8;
    bf16x8 ah = *(const bf16x8*)(pAh + ko);
    bf16x8 al = *(const bf16x8*)(pAl + ko);
    #pragma unroll
    for (int gt_ = 0; gt_ < 3; ++gt_){
      bf16x8 wh = *(const bf16x8*)(pW[gt_] + ko);
      bf16x8 wl = *(const bf16x8*)(pWl[gt_] + ko);
      acc[gt_] = MFMA16(ah, wh, acc[gt_], 0,0,0);
      acc[gt_] = MFMA16(al, wh, acc[gt_], 0,0,0);
      acc[gt_] = MFMA16(ah, wl, acc[gt_], 0,0,0);
    }
  }
  const int c = c0 + lr;
  #pragma unroll
  for (int reg = 0; reg < 4; ++reg){
    int b = g*16 + lk*4 + reg;
    float gir = acc[0][reg] + G2F[(long)b*1536 + c];
    float giz = acc[1][reg] + G2F[(long)b*1536 + 512 + c];
    float gin = acc[2][reg] + G2F[(long)b*1536 + 1024 + c];
    float ghr = GHH2F[(long)b*1536 + c];
    float ghz = GHH2F[(long)b*1536 + 512 + c];
    float ghn = GHH2F[(long)b*1536 + 1024 + c];
    float r_ = sigm(gir + ghr);
    float z_ = sigm(giz + ghz);
    float n_ = tanhf(gin + r_*ghn);
    float hold = bf2f(h2hiO[b*512 + c]) + bf2f(h2loO[b*512 + c]);
    float hv = (1.f - z_)*n_ + z_*hold;
    u16 hh = f2bf(hv);
    h2hiN[b*512 + c] = hh;
    h2loN[b*512 + c] = f2bf(hv - bf2f(hh));
    h2bf[((long)b*20 + t)*512 + c] = hh;
  }
}

// ---------------- host launch ----------------
extern "C" void kernel_launch(void* const* d_in, const int* in_sizes, int n_in,
                              void* d_out, int out_size, void* d_ws, size_t ws_size,
                              hipStream_t stream){
  const float* fv   = (const float*)d_in[0];
  const float* gt   = (const float*)d_in[2];
  const float* awih = (const float*)d_in[3];
  const float* awhh = (const float*)d_in[4];
  const float* abih = (const float*)d_in[5];
  const float* abhh = (const float*)d_in[6];
  const float* lwih = (const float*)d_in[7];
  const float* lwhh = (const float*)d_in[8];
  const float* lbih = (const float*)d_in[9];
  const float* lbhh = (const float*)d_in[10];
  const float* fc1w = (const float*)d_in[11];
  const float* fc1b = (const float*)d_in[12];
  const float* fc2w = (const float*)d_in[13];
  const float* fc2b = (const float*)d_in[14];
  const float* fc3w = (const float*)d_in[15];
  const float* db   = (const float*)d_in[18];
  const float* dw   = (const float*)d_in[17];
  char* ws = (char*)d_ws;
  float* out = (float*)d_out;

  k_prep0<<<dim3(2048), dim3(256), 0, stream>>>(fv, gt, awih, awhh, lwih, lwhh, ws);
  k_prep1<<<dim3(1536), dim3(256), 0, stream>>>(fv, awih, abih, fc1w, fc1b, ws);
  // PREX[b*21+t][1536] = x_t @ Wmid^T
  k_gemm_bf16<<<dim3(20, 11), dim3(256), 0, stream>>>(
      (const u16*)(ws + OFF_GTBF), (const u16*)(ws + OFF_WMIDBF),
      (const float*)nullptr, (float*)(ws + OFF_PREX), 1344, 1536);
  for (int t = 0; t < 20; ++t){
    int pa = t & 1;
    k_phaseA<<<dim3(48), dim3(256), 0, stream>>>(ws, abhh, lbhh, t, pa);
    k_phaseB<<<dim3(80), dim3(256), 0, stream>>>(ws, fv, fc2w, fc2b, fc3w, lbih, pa);
    k_phaseC<<<dim3(32), dim3(256), 0, stream>>>(ws, t, pa);
  }
  // logits = H2seq @ dense_w^T + db  (W converted on the fly)
  k_gemm_vocab<<<dim3(250, 10), dim3(256), 0, stream>>>(
      (const u16*)(ws + OFF_H2BF), dw, db, out, 1280, 20000);
}

// Round 4
// 1358.225 us; speedup vs baseline: 12.9120x; 1.9784x over previous
//
#include <hip/hip_runtime.h>
#include <hip/hip_bf16.h>
#include <math.h>

// B=64, steps=20 (T=21), L=36, E=512, H=512, F=1024, VOC=20000
// att_in=2048 (h2|x_t|v_mean), lang_in=1536 (mix|h1), 3H=1536
// Gate GEMMs: M=16 per batch-group MFMA, bf16 hi/lo split (3-MFMA ~fp32 quality).
// Round-3: 512-thr blocks with 8-way wave split-K + LDS reduce (occupancy fix),
//          vocab W pre-converted to bf16 in dead-ws overlay + XCD-chunked swizzle.

typedef __attribute__((ext_vector_type(8))) short bf16x8;
typedef __attribute__((ext_vector_type(4))) float f32x4;
typedef unsigned short u16;
typedef unsigned int u32;

#define MFMA16 __builtin_amdgcn_mfma_f32_16x16x32_bf16

__device__ __forceinline__ u16 f2bf(float f){
  u32 u = __float_as_uint(f);
  u += 0x7fffu + ((u >> 16) & 1u);
  return (u16)(u >> 16);
}
__device__ __forceinline__ float bf2f(u16 u){ return __uint_as_float(((u32)u) << 16); }
__device__ __forceinline__ float sigm(float x){ return 1.0f/(1.0f+__expf(-x)); }

// ---------------- workspace layout (bytes) ----------------
#define OFF_VMEAN  ((size_t)0)           // 64*1024 f32
#define OFF_VMW    ((size_t)262144)      // 64*1536 f32
#define OFF_VW     ((size_t)655360)      // 64*36*128 f32
#define OFF_PREX   ((size_t)1835008)     // 1344*1536 f32
#define OFF_GTBF   ((size_t)10092544)    // 1344*512 bf16
#define OFF_WMIDBF ((size_t)11468800)    // 1536*512 bf16
#define OFF_WIH2HI ((size_t)13041664)    // 1536*512 bf16 each below
#define OFF_WIH2LO ((size_t)14614528)
#define OFF_AWHHHI ((size_t)16187392)
#define OFF_AWHHLO ((size_t)17760256)
#define OFF_LWHHHI ((size_t)19333120)
#define OFF_LWHHLO ((size_t)20905984)
#define OFF_LWIHHI ((size_t)22478848)    // 1536*1536 bf16
#define OFF_LWIHLO ((size_t)27197440)
#define OFF_H1HI   ((size_t)31916032)    // 2*64*512 u16 (parity dbuf)
#define OFF_H1LO   ((size_t)32047104)
#define OFF_H2HI   ((size_t)32178176)
#define OFF_H2LO   ((size_t)32309248)
#define OFF_MIXHI  ((size_t)32440320)    // 64*1024 u16
#define OFF_MIXLO  ((size_t)32571392)
#define OFF_G2F    ((size_t)32702464)    // 64*1536 f32
#define OFF_GHH2F  ((size_t)33095680)    // 64*1536 f32
#define OFF_H2BF   ((size_t)33488896)    // 1280*512 bf16
// total 34,799,616 B (same as round-2, proven to fit)
// OVERLAY (valid only after last phaseC; rebuilt by prep each call):
#define OFF_WDBF   ((size_t)0)           // 20000*512 bf16 = 20,480,000 < OFF_H1HI  ✓

// ---------------- prep0: zeros, bf16 + hi/lo conversions, v_mean ----------------
__global__ __launch_bounds__(256) void k_prep0(
    const float* __restrict__ fv, const float* __restrict__ gt,
    const float* __restrict__ awih, const float* __restrict__ awhh,
    const float* __restrict__ lwih, const float* __restrict__ lwhh,
    char* __restrict__ ws){
  long gid = (long)blockIdx.x * blockDim.x + threadIdx.x;
  long stride = (long)gridDim.x * blockDim.x;
  u32* zh1h = (u32*)(ws + OFF_H1HI);
  u32* zh1l = (u32*)(ws + OFF_H1LO);
  u32* zh2h = (u32*)(ws + OFF_H2HI);
  u32* zh2l = (u32*)(ws + OFF_H2LO);
  for (long i = gid; i < 16384; i += stride){ zh1h[i]=0; zh1l[i]=0; zh2h[i]=0; zh2l[i]=0; }
  u16* gtbf = (u16*)(ws + OFF_GTBF);
  for (long i = gid; i < 688128; i += stride) gtbf[i] = f2bf(gt[i]);
  u16* wmid = (u16*)(ws + OFF_WMIDBF);
  for (long i = gid; i < 786432; i += stride)
    wmid[i] = f2bf(awih[(i>>9)*2048 + 512 + (i&511)]);
  u16* w2h = (u16*)(ws + OFF_WIH2HI); u16* w2l = (u16*)(ws + OFF_WIH2LO);
  for (long i = gid; i < 786432; i += stride){
    float x = awih[(i>>9)*2048 + (i&511)];
    u16 h = f2bf(x); w2h[i] = h; w2l[i] = f2bf(x - bf2f(h));
  }
  u16* ahh = (u16*)(ws + OFF_AWHHHI); u16* ahl = (u16*)(ws + OFF_AWHHLO);
  for (long i = gid; i < 786432; i += stride){
    float x = awhh[i]; u16 h = f2bf(x); ahh[i] = h; ahl[i] = f2bf(x - bf2f(h));
  }
  u16* lhh = (u16*)(ws + OFF_LWHHHI); u16* lhl = (u16*)(ws + OFF_LWHHLO);
  for (long i = gid; i < 786432; i += stride){
    float x = lwhh[i]; u16 h = f2bf(x); lhh[i] = h; lhl[i] = f2bf(x - bf2f(h));
  }
  u16* lih = (u16*)(ws + OFF_LWIHHI); u16* lil = (u16*)(ws + OFF_LWIHLO);
  for (long i = gid; i < 2359296; i += stride){
    float x = lwih[i]; u16 h = f2bf(x); lih[i] = h; lil[i] = f2bf(x - bf2f(h));
  }
  float* vmean = (float*)(ws + OFF_VMEAN);
  for (long i = gid; i < 65536; i += stride){
    long b = i >> 10, f = i & 1023;
    float s = 0.f;
    for (int l = 0; l < 36; ++l) s += fv[b*36864 + l*1024 + f];
    vmean[i] = s * (1.f/36.f);
  }
}

// ---------------- prep1: VMW = b_ih + v_mean@Wright^T ; v_w = fv@fc1^T + b ----------------
__global__ __launch_bounds__(256) void k_prep1(const float* __restrict__ fv,
    const float* __restrict__ att_w_ih, const float* __restrict__ att_b_ih,
    const float* __restrict__ fc1_w, const float* __restrict__ fc1_b,
    char* __restrict__ ws){
  const float* vmean = (const float*)(ws + OFF_VMEAN);
  float* vmw = (float*)(ws + OFF_VMW);
  float* vwp = (float*)(ws + OFF_VW);
  long gid = (long)blockIdx.x * blockDim.x + threadIdx.x;
  if (gid < 98304){
    long b = gid / 1536, j = gid % 1536;
    const float4* x = (const float4*)(vmean + b*1024);
    const float4* w = (const float4*)(att_w_ih + j*2048 + 1024);
    float s = att_b_ih[j];
    #pragma unroll 8
    for (int k = 0; k < 256; ++k){
      float4 a = x[k], c = w[k];
      s += a.x*c.x + a.y*c.y + a.z*c.z + a.w*c.w;
    }
    vmw[gid] = s;
  } else {
    long i = gid - 98304;              // < 294912
    long bl = i >> 7, c = i & 127;
    const float4* x = (const float4*)(fv + bl*1024);
    const float4* w = (const float4*)(fc1_w + c*1024);
    float s = fc1_b[c];
    #pragma unroll 8
    for (int k = 0; k < 256; ++k){
      float4 a = x[k], ww = w[k];
      s += a.x*ww.x + a.y*ww.y + a.z*ww.z + a.w*ww.w;
    }
    vwp[i] = s;
  }
}

// ---------------- generic bf16 MFMA GEMM, K=512 (used for PREX) ----------------
__global__ __launch_bounds__(256) void k_gemm_bf16(
    const u16* __restrict__ A, const u16* __restrict__ W,
    const float* __restrict__ bias, float* __restrict__ C, int M, int N){
  const int bn = blockIdx.x * 80, bm = blockIdx.y * 128;
  const int tid = threadIdx.x, w = tid >> 6, l = tid & 63;
  const int lr = l & 15, lk = l >> 4;
  f32x4 acc[2][5];
  #pragma unroll
  for (int i = 0; i < 2; ++i)
    #pragma unroll
    for (int j = 0; j < 5; ++j) acc[i][j] = (f32x4){0.f,0.f,0.f,0.f};
  long ar[2], wr[5];
  #pragma unroll
  for (int mi = 0; mi < 2; ++mi) ar[mi] = (long)min(bm + w*32 + mi*16 + lr, M-1) * 512;
  #pragma unroll
  for (int ni = 0; ni < 5; ++ni) wr[ni] = (long)min(bn + ni*16 + lr, N-1) * 512;
  for (int ks = 0; ks < 16; ++ks){
    int ko = ks*32 + lk*8;
    bf16x8 a0 = *(const bf16x8*)(A + ar[0] + ko);
    bf16x8 a1 = *(const bf16x8*)(A + ar[1] + ko);
    #pragma unroll
    for (int ni = 0; ni < 5; ++ni){
      bf16x8 wb = *(const bf16x8*)(W + wr[ni] + ko);
      acc[0][ni] = MFMA16(a0, wb, acc[0][ni], 0,0,0);
      acc[1][ni] = MFMA16(a1, wb, acc[1][ni], 0,0,0);
    }
  }
  #pragma unroll
  for (int mi = 0; mi < 2; ++mi){
    int row0 = bm + w*32 + mi*16 + lk*4;
    #pragma unroll
    for (int ni = 0; ni < 5; ++ni){
      int col = bn + ni*16 + lr;
      if (col < N){
        float bv = bias ? bias[col] : 0.f;
        #pragma unroll
        for (int r2 = 0; r2 < 4; ++r2){
          int row = row0 + r2;
          if (row < M) C[(long)row*N + col] = acc[mi][ni][r2] + bv;
        }
      }
    }
  }
}

// ---------------- dense_w fp32 -> bf16 (into dead-ws overlay) ----------------
__global__ __launch_bounds__(256) void k_cvt_dense(const float* __restrict__ dw,
                                                   char* __restrict__ ws){
  ushort4* out = (ushort4*)(ws + OFF_WDBF);
  long gid = (long)blockIdx.x * blockDim.x + threadIdx.x;
  long stride = (long)gridDim.x * blockDim.x;
  for (long i = gid; i < 2560000; i += stride){
    float4 v = ((const float4*)dw)[i];
    ushort4 o;
    o.x = f2bf(v.x); o.y = f2bf(v.y); o.z = f2bf(v.z); o.w = f2bf(v.w);
    out[i] = o;
  }
}

// ---------------- vocab GEMM: M=1280 N=20000 K=512, bf16 W, XCD-chunked swizzle ----
__global__ __launch_bounds__(256) void k_gemm_vocab(
    const u16* __restrict__ A, const u16* __restrict__ W,
    const float* __restrict__ bias, float* __restrict__ C){
  // bijective XCD swizzle (nwg=2500: q=312, r=4), bm fastest within chunk
  int flat = blockIdx.x;
  int xcd = flat & 7, idx = flat >> 3;
  int wg = (xcd < 4 ? xcd*313 : 4*313 + (xcd-4)*312) + idx;
  const int bm = (wg % 10) * 128;
  const int bn = (wg / 10) * 80;
  const int tid = threadIdx.x, w = tid >> 6, l = tid & 63;
  const int lr = l & 15, lk = l >> 4;
  f32x4 acc[2][5];
  #pragma unroll
  for (int i = 0; i < 2; ++i)
    #pragma unroll
    for (int j = 0; j < 5; ++j) acc[i][j] = (f32x4){0.f,0.f,0.f,0.f};
  long ar[2], wr[5];
  #pragma unroll
  for (int mi = 0; mi < 2; ++mi) ar[mi] = (long)(bm + w*32 + mi*16 + lr) * 512;
  #pragma unroll
  for (int ni = 0; ni < 5; ++ni) wr[ni] = (long)(bn + ni*16 + lr) * 512;
  for (int ks = 0; ks < 16; ++ks){
    int ko = ks*32 + lk*8;
    bf16x8 a0 = *(const bf16x8*)(A + ar[0] + ko);
    bf16x8 a1 = *(const bf16x8*)(A + ar[1] + ko);
    #pragma unroll
    for (int ni = 0; ni < 5; ++ni){
      bf16x8 wb = *(const bf16x8*)(W + wr[ni] + ko);
      acc[0][ni] = MFMA16(a0, wb, acc[0][ni], 0,0,0);
      acc[1][ni] = MFMA16(a1, wb, acc[1][ni], 0,0,0);
    }
  }
  #pragma unroll
  for (int mi = 0; mi < 2; ++mi){
    int row0 = bm + w*32 + mi*16 + lk*4;
    #pragma unroll
    for (int ni = 0; ni < 5; ++ni){
      int col = bn + ni*16 + lr;
      float bv = bias[col];
      #pragma unroll
      for (int r2 = 0; r2 < 4; ++r2)
        C[(long)(row0 + r2)*20000 + col] = acc[mi][ni][r2] + bv;
    }
  }
}

// ---------------- phase A: att-GRU (split-K 4 x {ih,hh} + fused combine) || GHH2 ----
__global__ __launch_bounds__(512) void k_phaseA(char* __restrict__ ws,
    const float* __restrict__ abhh, const float* __restrict__ lbhh, int t, int pa){
  __shared__ float ldsF[6144];
  const int blk = blockIdx.x, tid = threadIdx.x;
  const int wid = tid >> 6, lane = tid & 63, lr = lane & 15, lk = lane >> 4;
  const int pn = pa ^ 1;
  const u16* h2hi = (const u16*)(ws + OFF_H2HI) + pa*32768;
  const u16* h2lo = (const u16*)(ws + OFF_H2LO) + pa*32768;
  if (blk < 128){
    const int g = blk >> 5, c0 = (blk & 31) * 16;
    const u16* h1hi = (const u16*)(ws + OFF_H1HI) + pa*32768;
    const u16* h1lo = (const u16*)(ws + OFF_H1LO) + pa*32768;
    u16* h1hiN = (u16*)(ws + OFF_H1HI) + pn*32768;
    u16* h1loN = (u16*)(ws + OFF_H1LO) + pn*32768;
    const int mat = wid & 1, kq = wid >> 1;
    const int bA = g*16 + lr;
    const u16 *pAh, *pAl, *wH, *wL;
    if (mat == 0){
      pAh = h2hi + bA*512; pAl = h2lo + bA*512;
      wH = (const u16*)(ws + OFF_WIH2HI); wL = (const u16*)(ws + OFF_WIH2LO);
    } else {
      pAh = h1hi + bA*512; pAl = h1lo + bA*512;
      wH = (const u16*)(ws + OFF_AWHHHI); wL = (const u16*)(ws + OFF_AWHHLO);
    }
    const u16 *pW[3], *pWl[3];
    #pragma unroll
    for (int gate = 0; gate < 3; ++gate){
      long r = gate*512 + c0 + lr;
      pW[gate] = wH + r*512; pWl[gate] = wL + r*512;
    }
    f32x4 acc[3];
    #pragma unroll
    for (int i = 0; i < 3; ++i) acc[i] = (f32x4){0,0,0,0};
    #pragma unroll
    for (int ks = 0; ks < 4; ++ks){
      const int ko = kq*128 + ks*32 + lk*8;
      bf16x8 ah = *(const bf16x8*)(pAh + ko);
      bf16x8 al = *(const bf16x8*)(pAl + ko);
      #pragma unroll
      for (int gate = 0; gate < 3; ++gate){
        bf16x8 wh = *(const bf16x8*)(pW[gate] + ko);
        bf16x8 wl = *(const bf16x8*)(pWl[gate] + ko);
        acc[gate] = MFMA16(ah, wh, acc[gate], 0,0,0);
        acc[gate] = MFMA16(al, wh, acc[gate], 0,0,0);
        acc[gate] = MFMA16(ah, wl, acc[gate], 0,0,0);
      }
    }
    #pragma unroll
    for (int gate = 0; gate < 3; ++gate)
      #pragma unroll
      for (int rg = 0; rg < 4; ++rg)
        ldsF[((wid*3 + gate)*4 + rg)*64 + lane] = acc[gate][rg];
    __syncthreads();
    if (tid < 256){
      const float* prex = (const float*)(ws + OFF_PREX);
      const float* vmw  = (const float*)(ws + OFF_VMW);
      const int l = tid & 63, rg = tid >> 6;
      const int c = c0 + (l & 15);
      const int b = g*16 + (l >> 4)*4 + rg;
      float gi[3], gh[3];
      #pragma unroll
      for (int gate = 0; gate < 3; ++gate){
        float si = 0.f, sh = 0.f;
        #pragma unroll
        for (int kq2 = 0; kq2 < 4; ++kq2){
          si += ldsF[(((2*kq2+0)*3 + gate)*4 + rg)*64 + l];
          sh += ldsF[(((2*kq2+1)*3 + gate)*4 + rg)*64 + l];
        }
        gi[gate] = si; gh[gate] = sh;
      }
      long pb = ((long)b*21 + t)*1536;
      float ir  = gi[0] + prex[pb + c]        + vmw[b*1536 + c];
      float iz  = gi[1] + prex[pb + 512 + c]  + vmw[b*1536 + 512 + c];
      float in_ = gi[2] + prex[pb + 1024 + c] + vmw[b*1536 + 1024 + c];
      float hr = gh[0] + abhh[c];
      float hz = gh[1] + abhh[512 + c];
      float hn = gh[2] + abhh[1024 + c];
      float r_ = sigm(ir + hr);
      float z_ = sigm(iz + hz);
      float n_ = tanhf(in_ + r_*hn);
      float hold = bf2f(h1hi[b*512 + c]) + bf2f(h1lo[b*512 + c]);
      float hv = (1.f - z_)*n_ + z_*hold;
      u16 hh = f2bf(hv);
      h1hiN[b*512 + c] = hh;
      h1loN[b*512 + c] = f2bf(hv - bf2f(hh));
    }
  } else {
    const int j = blk - 128;
    const int g = j / 24, rb = j % 24, r0 = rb*64;
    const int tile = wid & 3, kh = wid >> 2;
    const u16* pAh = h2hi + (g*16 + lr)*512;
    const u16* pAl = h2lo + (g*16 + lr)*512;
    const int rr = r0 + tile*16 + lr;
    const u16* pW  = (const u16*)(ws + OFF_LWHHHI) + (long)rr*512;
    const u16* pWl = (const u16*)(ws + OFF_LWHHLO) + (long)rr*512;
    f32x4 acc = (f32x4){0,0,0,0};
    #pragma unroll
    for (int ks = 0; ks < 8; ++ks){
      const int ko = kh*256 + ks*32 + lk*8;
      bf16x8 ah = *(const bf16x8*)(pAh + ko);
      bf16x8 al = *(const bf16x8*)(pAl + ko);
      bf16x8 wh = *(const bf16x8*)(pW + ko);
      bf16x8 wl = *(const bf16x8*)(pWl + ko);
      acc = MFMA16(ah, wh, acc, 0,0,0);
      acc = MFMA16(al, wh, acc, 0,0,0);
      acc = MFMA16(ah, wl, acc, 0,0,0);
    }
    #pragma unroll
    for (int rg = 0; rg < 4; ++rg)
      ldsF[((kh*4 + tile)*4 + rg)*64 + lane] = acc[rg];
    __syncthreads();
    float* GHH2F = (float*)(ws + OFF_GHH2F);
    #pragma unroll
    for (int rep = 0; rep < 2; ++rep){
      int idx = tid + rep*512;
      int tl = idx >> 8, rem = idx & 255;
      int l = rem & 63, rg = rem >> 6;
      int rrr = r0 + tl*16 + (l & 15);
      int b = g*16 + (l >> 4)*4 + rg;
      float v = ldsF[((0 + tl)*4 + rg)*64 + l] + ldsF[((4 + tl)*4 + rg)*64 + l] + lbhh[rrr];
      GHH2F[(long)b*1536 + rrr] = v;
    }
  }
}

// ---------------- phase B: G2 (lang ih h1-part, split-K) || attention path ----------
__global__ __launch_bounds__(512) void k_phaseB(char* __restrict__ ws,
    const float* __restrict__ fv,
    const float* __restrict__ fc2w, const float* __restrict__ fc2b,
    const float* __restrict__ fc3w, const float* __restrict__ lbih, int pa){
  __shared__ float ldsF[2048];
  const int blk = blockIdx.x, tid = threadIdx.x;
  const int pn = pa ^ 1;
  const u16* h1hi = (const u16*)(ws + OFF_H1HI) + pn*32768;
  const u16* h1lo = (const u16*)(ws + OFF_H1LO) + pn*32768;
  if (blk < 96){
    const int wid = tid >> 6, lane = tid & 63, lr = lane & 15, lk = lane >> 4;
    const int g = blk / 24, rb = blk % 24, r0 = rb*64;
    const int tile = wid & 3, kh = wid >> 2;
    const u16* pAh = h1hi + (g*16 + lr)*512;
    const u16* pAl = h1lo + (g*16 + lr)*512;
    const int rr = r0 + tile*16 + lr;
    const u16* pW  = (const u16*)(ws + OFF_LWIHHI) + (long)rr*1536 + 1024;
    const u16* pWl = (const u16*)(ws + OFF_LWIHLO) + (long)rr*1536 + 1024;
    f32x4 acc = (f32x4){0,0,0,0};
    #pragma unroll
    for (int ks = 0; ks < 8; ++ks){
      const int ko = kh*256 + ks*32 + lk*8;
      bf16x8 ah = *(const bf16x8*)(pAh + ko);
      bf16x8 al = *(const bf16x8*)(pAl + ko);
      bf16x8 wh = *(const bf16x8*)(pW + ko);
      bf16x8 wl = *(const bf16x8*)(pWl + ko);
      acc = MFMA16(ah, wh, acc, 0,0,0);
      acc = MFMA16(al, wh, acc, 0,0,0);
      acc = MFMA16(ah, wl, acc, 0,0,0);
    }
    #pragma unroll
    for (int rg = 0; rg < 4; ++rg)
      ldsF[((kh*4 + tile)*4 + rg)*64 + lane] = acc[rg];
    __syncthreads();
    float* G2F = (float*)(ws + OFF_G2F);
    #pragma unroll
    for (int rep = 0; rep < 2; ++rep){
      int idx = tid + rep*512;
      int tl = idx >> 8, rem = idx & 255;
      int l = rem & 63, rg = rem >> 6;
      int rrr = r0 + tl*16 + (l & 15);
      int b = g*16 + (l >> 4)*4 + rg;
      float v = ldsF[((0 + tl)*4 + rg)*64 + l] + ldsF[((4 + tl)*4 + rg)*64 + l] + lbih[rrr];
      G2F[(long)b*1536 + rrr] = v;
    }
  } else {
    const int b = blk - 96;
    const float* vw = (const float*)(ws + OFF_VW);
    u16* mixhi = (u16*)(ws + OFF_MIXHI);
    u16* mixlo = (u16*)(ws + OFF_MIXLO);
    float* sh1 = ldsF;          // 512
    float* hwS = ldsF + 512;    // 128
    float* sS  = ldsF + 640;    // 36
    float* aS  = ldsF + 680;    // 36
    sh1[tid] = bf2f(h1hi[b*512 + tid]) + bf2f(h1lo[b*512 + tid]);
    __syncthreads();
    {
      int c = tid >> 2, q = tid & 3;
      const float4* x = (const float4*)(sh1 + q*128);
      const float4* w = (const float4*)(fc2w + c*512 + q*128);
      float s = 0.f;
      #pragma unroll 8
      for (int i = 0; i < 32; ++i){
        float4 a = x[i], ww = w[i];
        s += a.x*ww.x + a.y*ww.y + a.z*ww.z + a.w*ww.w;
      }
      s += __shfl_xor(s, 1); s += __shfl_xor(s, 2);
      if (q == 0) hwS[c] = s + fc2b[c];
    }
    __syncthreads();
    {
      int jj = tid & 15, l0 = tid >> 4;
      #pragma unroll
      for (int lb = 0; lb < 64; lb += 32){
        int l = lb + l0;
        float s = 0.f;
        if (l < 36){
          const float* vr = vw + (long)b*4608 + l*128;
          #pragma unroll
          for (int k = jj*8; k < jj*8 + 8; ++k) s += tanhf(vr[k] + hwS[k]) * fc3w[k];
        }
        s += __shfl_xor(s,1); s += __shfl_xor(s,2); s += __shfl_xor(s,4); s += __shfl_xor(s,8);
        if (jj == 0 && l < 36) sS[l] = s;
      }
    }
    __syncthreads();
    if (tid == 0){
      float m = -1e30f;
      for (int l = 0; l < 36; ++l) m = fmaxf(m, sS[l]);
      float sum = 0.f;
      for (int l = 0; l < 36; ++l){ float e = __expf(sS[l] - m); aS[l] = e; sum += e; }
      float inv = 1.f / sum;
      for (int l = 0; l < 36; ++l) aS[l] *= inv;
    }
    __syncthreads();
    {
      float ax = 0.f, ay = 0.f;
      const float* base = fv + (long)b*36864 + tid*2;
      for (int l = 0; l < 36; ++l){
        float a = aS[l];
        float2 v = *(const float2*)(base + l*1024);
        ax += a*v.x; ay += a*v.y;
      }
      ushort2 hi2, lo2; u16 h;
      h = f2bf(ax); hi2.x = h; lo2.x = f2bf(ax - bf2f(h));
      h = f2bf(ay); hi2.y = h; lo2.y = f2bf(ay - bf2f(h));
      *(ushort2*)(mixhi + b*1024 + tid*2) = hi2;
      *(ushort2*)(mixlo + b*1024 + tid*2) = lo2;
    }
  }
}

// ---------------- phase C: lang-GRU mix-part (split-K 8) + fused h2 combine --------
__global__ __launch_bounds__(512) void k_phaseC(char* __restrict__ ws, int t, int pa){
  __shared__ float ldsF[6144];
  const int blk = blockIdx.x, tid = threadIdx.x;
  const int wid = tid >> 6, lane = tid & 63, lr = lane & 15, lk = lane >> 4;
  const int pn = pa ^ 1;
  const int g = blk >> 5, c0 = (blk & 31) * 16;
  const u16* mixhi = (const u16*)(ws + OFF_MIXHI);
  const u16* mixlo = (const u16*)(ws + OFF_MIXLO);
  const u16* lih = (const u16*)(ws + OFF_LWIHHI);
  const u16* lil = (const u16*)(ws + OFF_LWIHLO);
  const int bA = g*16 + lr;
  const u16* pAh = mixhi + bA*1024;
  const u16* pAl = mixlo + bA*1024;
  const u16 *pW[3], *pWl[3];
  #pragma unroll
  for (int gate = 0; gate < 3; ++gate){
    long r = gate*512 + c0 + lr;
    pW[gate] = lih + r*1536; pWl[gate] = lil + r*1536;
  }
  f32x4 acc[3];
  #pragma unroll
  for (int i = 0; i < 3; ++i) acc[i] = (f32x4){0,0,0,0};
  #pragma unroll
  for (int ks = 0; ks < 4; ++ks){
    const int ko = wid*128 + ks*32 + lk*8;
    bf16x8 ah = *(const bf16x8*)(pAh + ko);
    bf16x8 al = *(const bf16x8*)(pAl + ko);
    #pragma unroll
    for (int gate = 0; gate < 3; ++gate){
      bf16x8 wh = *(const bf16x8*)(pW[gate] + ko);
      bf16x8 wl = *(const bf16x8*)(pWl[gate] + ko);
      acc[gate] = MFMA16(ah, wh, acc[gate], 0,0,0);
      acc[gate] = MFMA16(al, wh, acc[gate], 0,0,0);
      acc[gate] = MFMA16(ah, wl, acc[gate], 0,0,0);
    }
  }
  #pragma unroll
  for (int gate = 0; gate < 3; ++gate)
    #pragma unroll
    for (int rg = 0; rg < 4; ++rg)
      ldsF[((wid*3 + gate)*4 + rg)*64 + lane] = acc[gate][rg];
  __syncthreads();
  if (tid < 256){
    const float* G2F   = (const float*)(ws + OFF_G2F);
    const float* GHH2F = (const float*)(ws + OFF_GHH2F);
    const u16* h2hiO = (const u16*)(ws + OFF_H2HI) + pa*32768;
    const u16* h2loO = (const u16*)(ws + OFF_H2LO) + pa*32768;
    u16* h2hiN = (u16*)(ws + OFF_H2HI) + pn*32768;
    u16* h2loN = (u16*)(ws + OFF_H2LO) + pn*32768;
    u16* h2bf  = (u16*)(ws + OFF_H2BF);
    const int l = tid & 63, rg = tid >> 6;
    const int c = c0 + (l & 15);
    const int b = g*16 + (l >> 4)*4 + rg;
    float gi[3];
    #pragma unroll
    for (int gate = 0; gate < 3; ++gate){
      float s = 0.f;
      #pragma unroll
      for (int w2 = 0; w2 < 8; ++w2)
        s += ldsF[((w2*3 + gate)*4 + rg)*64 + l];
      gi[gate] = s;
    }
    float gir = gi[0] + G2F[(long)b*1536 + c];
    float giz = gi[1] + G2F[(long)b*1536 + 512 + c];
    float gin = gi[2] + G2F[(long)b*1536 + 1024 + c];
    float ghr = GHH2F[(long)b*1536 + c];
    float ghz = GHH2F[(long)b*1536 + 512 + c];
    float ghn = GHH2F[(long)b*1536 + 1024 + c];
    float r_ = sigm(gir + ghr);
    float z_ = sigm(giz + ghz);
    float n_ = tanhf(gin + r_*ghn);
    float hold = bf2f(h2hiO[b*512 + c]) + bf2f(h2loO[b*512 + c]);
    float hv = (1.f - z_)*n_ + z_*hold;
    u16 hh = f2bf(hv);
    h2hiN[b*512 + c] = hh;
    h2loN[b*512 + c] = f2bf(hv - bf2f(hh));
    h2bf[((long)b*20 + t)*512 + c] = hh;
  }
}

// ---------------- host launch ----------------
extern "C" void kernel_launch(void* const* d_in, const int* in_sizes, int n_in,
                              void* d_out, int out_size, void* d_ws, size_t ws_size,
                              hipStream_t stream){
  const float* fv   = (const float*)d_in[0];
  const float* gt   = (const float*)d_in[2];
  const float* awih = (const float*)d_in[3];
  const float* awhh = (const float*)d_in[4];
  const float* abih = (const float*)d_in[5];
  const float* abhh = (const float*)d_in[6];
  const float* lwih = (const float*)d_in[7];
  const float* lwhh = (const float*)d_in[8];
  const float* lbih = (const float*)d_in[9];
  const float* lbhh = (const float*)d_in[10];
  const float* fc1w = (const float*)d_in[11];
  const float* fc1b = (const float*)d_in[12];
  const float* fc2w = (const float*)d_in[13];
  const float* fc2b = (const float*)d_in[14];
  const float* fc3w = (const float*)d_in[15];
  const float* dw   = (const float*)d_in[17];
  const float* db   = (const float*)d_in[18];
  char* ws = (char*)d_ws;
  float* out = (float*)d_out;

  k_prep0<<<dim3(2048), dim3(256), 0, stream>>>(fv, gt, awih, awhh, lwih, lwhh, ws);
  k_prep1<<<dim3(1536), dim3(256), 0, stream>>>(fv, awih, abih, fc1w, fc1b, ws);
  k_gemm_bf16<<<dim3(20, 11), dim3(256), 0, stream>>>(
      (const u16*)(ws + OFF_GTBF), (const u16*)(ws + OFF_WMIDBF),
      (const float*)nullptr, (float*)(ws + OFF_PREX), 1344, 1536);
  for (int t = 0; t < 20; ++t){
    int pa = t & 1;
    k_phaseA<<<dim3(224), dim3(512), 0, stream>>>(ws, abhh, lbhh, t, pa);
    k_phaseB<<<dim3(160), dim3(512), 0, stream>>>(ws, fv, fc2w, fc2b, fc3w, lbih, pa);
    k_phaseC<<<dim3(128), dim3(512), 0, stream>>>(ws, t, pa);
  }
  // dense_w -> bf16 into dead-ws overlay (safe after last phaseC), then vocab GEMM
  k_cvt_dense<<<dim3(2048), dim3(256), 0, stream>>>(dw, ws);
  k_gemm_vocab<<<dim3(2500), dim3(256), 0, stream>>>(
      (const u16*)(ws + OFF_H2BF), (const u16*)(ws + OFF_WDBF), db, out);
}

// Round 5
// 1291.917 us; speedup vs baseline: 13.5747x; 1.0513x over previous
//
#include <hip/hip_runtime.h>
#include <hip/hip_bf16.h>
#include <math.h>

// B=64, steps=20 (T=21), L=36, E=512, H=512, F=1024, VOC=20000
// Gate GEMMs: M=16 per batch-group MFMA, bf16 hi/lo split (3-MFMA ~fp32 quality).
// Round-5: prep1 -> MFMA (k_prep_gemm); G2+GHH2 folded into phaseC (no global
//          round-trip); phaseA=128, phaseB=64 (attn only), phaseC=128 blocks.

typedef __attribute__((ext_vector_type(8))) short bf16x8;
typedef __attribute__((ext_vector_type(4))) float f32x4;
typedef unsigned short u16;
typedef unsigned int u32;

#define MFMA16 __builtin_amdgcn_mfma_f32_16x16x32_bf16

__device__ __forceinline__ u16 f2bf(float f){
  u32 u = __float_as_uint(f);
  u += 0x7fffu + ((u >> 16) & 1u);
  return (u16)(u >> 16);
}
__device__ __forceinline__ float bf2f(u16 u){ return __uint_as_float(((u32)u) << 16); }
__device__ __forceinline__ float sigm(float x){ return 1.0f/(1.0f+__expf(-x)); }

// ---------------- workspace layout (bytes) ----------------
#define OFF_VMW    ((size_t)262144)      // 64*1536 f32 (b_ih + v_mean@Wright^T)
#define OFF_VW     ((size_t)655360)      // 64*36*128 f32
#define OFF_PREX   ((size_t)1835008)     // 1344*1536 f32
#define OFF_GTBF   ((size_t)10092544)    // 1344*512 bf16
#define OFF_WMIDBF ((size_t)11468800)    // 1536*512 bf16
#define OFF_WIH2HI ((size_t)13041664)    // 1536*512 bf16 each below
#define OFF_WIH2LO ((size_t)14614528)
#define OFF_AWHHHI ((size_t)16187392)
#define OFF_AWHHLO ((size_t)17760256)
#define OFF_LWHHHI ((size_t)19333120)
#define OFF_LWHHLO ((size_t)20905984)
#define OFF_LWIHHI ((size_t)22478848)    // 1536*1536 bf16
#define OFF_LWIHLO ((size_t)27197440)
#define OFF_H1HI   ((size_t)31916032)    // 2*64*512 u16 (parity dbuf)
#define OFF_H1LO   ((size_t)32047104)
#define OFF_H2HI   ((size_t)32178176)
#define OFF_H2LO   ((size_t)32309248)
#define OFF_MIXHI  ((size_t)32440320)    // 64*1024 u16
#define OFF_MIXLO  ((size_t)32571392)
#define OFF_H2BF   ((size_t)33488896)    // 1280*512 bf16 -> ends 34,799,616
// ---- prep-only hi/lo inputs (read before the t-loop only) ----
#define OFF_FVHI   ((size_t)34799616)    // 64*36*1024 bf16 = 4718592
#define OFF_FVLO   ((size_t)39518208)
#define OFF_WR1HI  ((size_t)44236800)    // 1536*1024 bf16 = 3145728
#define OFF_WR1LO  ((size_t)47382528)
#define OFF_FC1HI  ((size_t)50528256)    // 128*1024 bf16 = 262144
#define OFF_FC1LO  ((size_t)50790400)
#define OFF_VMHI   ((size_t)51052544)    // 64*1024 bf16 = 131072
#define OFF_VMLO   ((size_t)51183616)    // ends 51,314,688 (< 55.3MB proven in r1)
// OVERLAY (valid only after last phaseC; rebuilt each call):
#define OFF_WDBF   ((size_t)0)           // 20000*512 bf16 = 20,480,000

// ---------------- prep0: zeros + all hi/lo conversions + v_mean ----------------
__global__ __launch_bounds__(256) void k_prep0(
    const float* __restrict__ fv, const float* __restrict__ gt,
    const float* __restrict__ awih, const float* __restrict__ awhh,
    const float* __restrict__ lwih, const float* __restrict__ lwhh,
    const float* __restrict__ fc1w, char* __restrict__ ws){
  long gid = (long)blockIdx.x * blockDim.x + threadIdx.x;
  long stride = (long)gridDim.x * blockDim.x;
  u32* zh1h = (u32*)(ws + OFF_H1HI);
  u32* zh1l = (u32*)(ws + OFF_H1LO);
  u32* zh2h = (u32*)(ws + OFF_H2HI);
  u32* zh2l = (u32*)(ws + OFF_H2LO);
  for (long i = gid; i < 16384; i += stride){ zh1h[i]=0; zh1l[i]=0; zh2h[i]=0; zh2l[i]=0; }
  u16* gtbf = (u16*)(ws + OFF_GTBF);
  for (long i = gid; i < 688128; i += stride) gtbf[i] = f2bf(gt[i]);
  u16* wmid = (u16*)(ws + OFF_WMIDBF);
  for (long i = gid; i < 786432; i += stride)
    wmid[i] = f2bf(awih[(i>>9)*2048 + (i&511) + 512]);
  u16* w2h = (u16*)(ws + OFF_WIH2HI); u16* w2l = (u16*)(ws + OFF_WIH2LO);
  for (long i = gid; i < 786432; i += stride){
    float x = awih[(i>>9)*2048 + (i&511)];
    u16 h = f2bf(x); w2h[i] = h; w2l[i] = f2bf(x - bf2f(h));
  }
  u16* ahh = (u16*)(ws + OFF_AWHHHI); u16* ahl = (u16*)(ws + OFF_AWHHLO);
  for (long i = gid; i < 786432; i += stride){
    float x = awhh[i]; u16 h = f2bf(x); ahh[i] = h; ahl[i] = f2bf(x - bf2f(h));
  }
  u16* lhh = (u16*)(ws + OFF_LWHHHI); u16* lhl = (u16*)(ws + OFF_LWHHLO);
  for (long i = gid; i < 786432; i += stride){
    float x = lwhh[i]; u16 h = f2bf(x); lhh[i] = h; lhl[i] = f2bf(x - bf2f(h));
  }
  u16* lih = (u16*)(ws + OFF_LWIHHI); u16* lil = (u16*)(ws + OFF_LWIHLO);
  for (long i = gid; i < 2359296; i += stride){
    float x = lwih[i]; u16 h = f2bf(x); lih[i] = h; lil[i] = f2bf(x - bf2f(h));
  }
  // fv hi/lo (for v_w MFMA)
  u16* fvh = (u16*)(ws + OFF_FVHI); u16* fvl = (u16*)(ws + OFF_FVLO);
  for (long i = gid; i < 2359296; i += stride){
    float x = fv[i]; u16 h = f2bf(x); fvh[i] = h; fvl[i] = f2bf(x - bf2f(h));
  }
  // att_w_ih right half (cols 1024..2047) hi/lo (for VMW MFMA)
  u16* wr1h = (u16*)(ws + OFF_WR1HI); u16* wr1l = (u16*)(ws + OFF_WR1LO);
  for (long i = gid; i < 1572864; i += stride){
    float x = awih[(i>>10)*2048 + 1024 + (i&1023)];
    u16 h = f2bf(x); wr1h[i] = h; wr1l[i] = f2bf(x - bf2f(h));
  }
  // fc1 hi/lo
  u16* f1h = (u16*)(ws + OFF_FC1HI); u16* f1l = (u16*)(ws + OFF_FC1LO);
  for (long i = gid; i < 131072; i += stride){
    float x = fc1w[i]; u16 h = f2bf(x); f1h[i] = h; f1l[i] = f2bf(x - bf2f(h));
  }
  // v_mean hi/lo
  u16* vmh = (u16*)(ws + OFF_VMHI); u16* vml = (u16*)(ws + OFF_VMLO);
  for (long i = gid; i < 65536; i += stride){
    long b = i >> 10, f = i & 1023;
    float s = 0.f;
    for (int l = 0; l < 36; ++l) s += fv[b*36864 + l*1024 + f];
    s *= (1.f/36.f);
    u16 h = f2bf(s); vmh[i] = h; vml[i] = f2bf(s - bf2f(h));
  }
}

// ---------------- prep_gemm: v_w (blk<144) and VMW (blk>=144), MFMA hi/lo ------
// 512 thr = 8 waves; each wave owns one 16x16 output tile, full-K loop.
__global__ __launch_bounds__(512) void k_prep_gemm(char* __restrict__ ws,
    const float* __restrict__ abih, const float* __restrict__ fc1b){
  const int blk = blockIdx.x, tid = threadIdx.x;
  const int wid = tid >> 6, lane = tid & 63, lr = lane & 15, lk = lane >> 4;
  f32x4 acc = (f32x4){0,0,0,0};
  if (blk < 144){
    // v_w[bl][c] = fv[bl,:] . fc1_w[c,:] + fc1_b[c]; M=2304, N=128, K=1024
    const u16* pAh = (const u16*)(ws + OFF_FVHI) + (long)(blk*16 + lr)*1024;
    const u16* pAl = (const u16*)(ws + OFF_FVLO) + (long)(blk*16 + lr)*1024;
    const int c = wid*16 + lr;
    const u16* pWh = (const u16*)(ws + OFF_FC1HI) + (long)c*1024;
    const u16* pWl = (const u16*)(ws + OFF_FC1LO) + (long)c*1024;
    for (int ks = 0; ks < 32; ++ks){
      const int ko = ks*32 + lk*8;
      bf16x8 ah = *(const bf16x8*)(pAh + ko);
      bf16x8 al = *(const bf16x8*)(pAl + ko);
      bf16x8 wh = *(const bf16x8*)(pWh + ko);
      bf16x8 wl = *(const bf16x8*)(pWl + ko);
      acc = MFMA16(ah, wh, acc, 0,0,0);
      acc = MFMA16(al, wh, acc, 0,0,0);
      acc = MFMA16(ah, wl, acc, 0,0,0);
    }
    float* vwp = (float*)(ws + OFF_VW);
    const int cc = wid*16 + lr;
    const float bv = fc1b[cc];
    #pragma unroll
    for (int rg = 0; rg < 4; ++rg){
      int row = blk*16 + lk*4 + rg;
      vwp[(long)row*128 + cc] = acc[rg] + bv;
    }
  } else {
    // VMW[b][j] = v_mean[b,:] . awih[j,1024:2048] + abih[j]; M=64, N=1536, K=1024
    const int unit = (blk - 144)*8 + wid;   // 0..383
    const int mtile = unit / 96, ntile = unit % 96;
    const u16* pAh = (const u16*)(ws + OFF_VMHI) + (long)(mtile*16 + lr)*1024;
    const u16* pAl = (const u16*)(ws + OFF_VMLO) + (long)(mtile*16 + lr)*1024;
    const int j = ntile*16 + lr;
    const u16* pWh = (const u16*)(ws + OFF_WR1HI) + (long)j*1024;
    const u16* pWl = (const u16*)(ws + OFF_WR1LO) + (long)j*1024;
    for (int ks = 0; ks < 32; ++ks){
      const int ko = ks*32 + lk*8;
      bf16x8 ah = *(const bf16x8*)(pAh + ko);
      bf16x8 al = *(const bf16x8*)(pAl + ko);
      bf16x8 wh = *(const bf16x8*)(pWh + ko);
      bf16x8 wl = *(const bf16x8*)(pWl + ko);
      acc = MFMA16(ah, wh, acc, 0,0,0);
      acc = MFMA16(al, wh, acc, 0,0,0);
      acc = MFMA16(ah, wl, acc, 0,0,0);
    }
    float* vmw = (float*)(ws + OFF_VMW);
    const float bv = abih[j];
    #pragma unroll
    for (int rg = 0; rg < 4; ++rg){
      int b = mtile*16 + lk*4 + rg;
      vmw[(long)b*1536 + j] = acc[rg] + bv;
    }
  }
}

// ---------------- generic bf16 MFMA GEMM, K=512 (used for PREX) ----------------
__global__ __launch_bounds__(256) void k_gemm_bf16(
    const u16* __restrict__ A, const u16* __restrict__ W,
    const float* __restrict__ bias, float* __restrict__ C, int M, int N){
  const int bn = blockIdx.x * 80, bm = blockIdx.y * 128;
  const int tid = threadIdx.x, w = tid >> 6, l = tid & 63;
  const int lr = l & 15, lk = l >> 4;
  f32x4 acc[2][5];
  #pragma unroll
  for (int i = 0; i < 2; ++i)
    #pragma unroll
    for (int j = 0; j < 5; ++j) acc[i][j] = (f32x4){0.f,0.f,0.f,0.f};
  long ar[2], wr[5];
  #pragma unroll
  for (int mi = 0; mi < 2; ++mi) ar[mi] = (long)min(bm + w*32 + mi*16 + lr, M-1) * 512;
  #pragma unroll
  for (int ni = 0; ni < 5; ++ni) wr[ni] = (long)min(bn + ni*16 + lr, N-1) * 512;
  for (int ks = 0; ks < 16; ++ks){
    int ko = ks*32 + lk*8;
    bf16x8 a0 = *(const bf16x8*)(A + ar[0] + ko);
    bf16x8 a1 = *(const bf16x8*)(A + ar[1] + ko);
    #pragma unroll
    for (int ni = 0; ni < 5; ++ni){
      bf16x8 wb = *(const bf16x8*)(W + wr[ni] + ko);
      acc[0][ni] = MFMA16(a0, wb, acc[0][ni], 0,0,0);
      acc[1][ni] = MFMA16(a1, wb, acc[1][ni], 0,0,0);
    }
  }
  #pragma unroll
  for (int mi = 0; mi < 2; ++mi){
    int row0 = bm + w*32 + mi*16 + lk*4;
    #pragma unroll
    for (int ni = 0; ni < 5; ++ni){
      int col = bn + ni*16 + lr;
      if (col < N){
        float bv = bias ? bias[col] : 0.f;
        #pragma unroll
        for (int r2 = 0; r2 < 4; ++r2){
          int row = row0 + r2;
          if (row < M) C[(long)row*N + col] = acc[mi][ni][r2] + bv;
        }
      }
    }
  }
}

// ---------------- dense_w fp32 -> bf16 (into dead-ws overlay) ----------------
__global__ __launch_bounds__(256) void k_cvt_dense(const float* __restrict__ dw,
                                                   char* __restrict__ ws){
  ushort4* out = (ushort4*)(ws + OFF_WDBF);
  long gid = (long)blockIdx.x * blockDim.x + threadIdx.x;
  long stride = (long)gridDim.x * blockDim.x;
  for (long i = gid; i < 2560000; i += stride){
    float4 v = ((const float4*)dw)[i];
    ushort4 o;
    o.x = f2bf(v.x); o.y = f2bf(v.y); o.z = f2bf(v.z); o.w = f2bf(v.w);
    out[i] = o;
  }
}

// ---------------- vocab GEMM: M=1280 N=20000 K=512, bf16 W, XCD-chunked swizzle ----
__global__ __launch_bounds__(256) void k_gemm_vocab(
    const u16* __restrict__ A, const u16* __restrict__ W,
    const float* __restrict__ bias, float* __restrict__ C){
  int flat = blockIdx.x;
  int xcd = flat & 7, idx = flat >> 3;
  int wg = (xcd < 4 ? xcd*313 : 4*313 + (xcd-4)*312) + idx;
  const int bm = (wg % 10) * 128;
  const int bn = (wg / 10) * 80;
  const int tid = threadIdx.x, w = tid >> 6, l = tid & 63;
  const int lr = l & 15, lk = l >> 4;
  f32x4 acc[2][5];
  #pragma unroll
  for (int i = 0; i < 2; ++i)
    #pragma unroll
    for (int j = 0; j < 5; ++j) acc[i][j] = (f32x4){0.f,0.f,0.f,0.f};
  long ar[2], wr[5];
  #pragma unroll
  for (int mi = 0; mi < 2; ++mi) ar[mi] = (long)(bm + w*32 + mi*16 + lr) * 512;
  #pragma unroll
  for (int ni = 0; ni < 5; ++ni) wr[ni] = (long)(bn + ni*16 + lr) * 512;
  for (int ks = 0; ks < 16; ++ks){
    int ko = ks*32 + lk*8;
    bf16x8 a0 = *(const bf16x8*)(A + ar[0] + ko);
    bf16x8 a1 = *(const bf16x8*)(A + ar[1] + ko);
    #pragma unroll
    for (int ni = 0; ni < 5; ++ni){
      bf16x8 wb = *(const bf16x8*)(W + wr[ni] + ko);
      acc[0][ni] = MFMA16(a0, wb, acc[0][ni], 0,0,0);
      acc[1][ni] = MFMA16(a1, wb, acc[1][ni], 0,0,0);
    }
  }
  #pragma unroll
  for (int mi = 0; mi < 2; ++mi){
    int row0 = bm + w*32 + mi*16 + lk*4;
    #pragma unroll
    for (int ni = 0; ni < 5; ++ni){
      int col = bn + ni*16 + lr;
      float bv = bias[col];
      #pragma unroll
      for (int r2 = 0; r2 < 4; ++r2)
        C[(long)(row0 + r2)*20000 + col] = acc[mi][ni][r2] + bv;
    }
  }
}

// ---------------- phase A: att-GRU (split-K 4 x {ih,hh} + fused combine) ----------
// grid 128 x 512thr. block=(g=blk>>5, c0=(blk&31)*16). wave: mat=wid&1, kq=wid>>1.
__global__ __launch_bounds__(512) void k_phaseA(char* __restrict__ ws,
    const float* __restrict__ abhh, int t, int pa){
  __shared__ float ldsF[6144];
  const int blk = blockIdx.x, tid = threadIdx.x;
  const int wid = tid >> 6, lane = tid & 63, lr = lane & 15, lk = lane >> 4;
  const int pn = pa ^ 1;
  const u16* h2hi = (const u16*)(ws + OFF_H2HI) + pa*32768;
  const u16* h2lo = (const u16*)(ws + OFF_H2LO) + pa*32768;
  const int g = blk >> 5, c0 = (blk & 31) * 16;
  const u16* h1hi = (const u16*)(ws + OFF_H1HI) + pa*32768;
  const u16* h1lo = (const u16*)(ws + OFF_H1LO) + pa*32768;
  u16* h1hiN = (u16*)(ws + OFF_H1HI) + pn*32768;
  u16* h1loN = (u16*)(ws + OFF_H1LO) + pn*32768;
  const int mat = wid & 1, kq = wid >> 1;
  const int bA = g*16 + lr;
  const u16 *pAh, *pAl, *wH, *wL;
  if (mat == 0){
    pAh = h2hi + bA*512; pAl = h2lo + bA*512;
    wH = (const u16*)(ws + OFF_WIH2HI); wL = (const u16*)(ws + OFF_WIH2LO);
  } else {
    pAh = h1hi + bA*512; pAl = h1lo + bA*512;
    wH = (const u16*)(ws + OFF_AWHHHI); wL = (const u16*)(ws + OFF_AWHHLO);
  }
  const u16 *pW[3], *pWl[3];
  #pragma unroll
  for (int gate = 0; gate < 3; ++gate){
    long r = gate*512 + c0 + lr;
    pW[gate] = wH + r*512; pWl[gate] = wL + r*512;
  }
  f32x4 acc[3];
  #pragma unroll
  for (int i = 0; i < 3; ++i) acc[i] = (f32x4){0,0,0,0};
  #pragma unroll
  for (int ks = 0; ks < 4; ++ks){
    const int ko = kq*128 + ks*32 + lk*8;
    bf16x8 ah = *(const bf16x8*)(pAh + ko);
    bf16x8 al = *(const bf16x8*)(pAl + ko);
    #pragma unroll
    for (int gate = 0; gate < 3; ++gate){
      bf16x8 wh = *(const bf16x8*)(pW[gate] + ko);
      bf16x8 wl = *(const bf16x8*)(pWl[gate] + ko);
      acc[gate] = MFMA16(ah, wh, acc[gate], 0,0,0);
      acc[gate] = MFMA16(al, wh, acc[gate], 0,0,0);
      acc[gate] = MFMA16(ah, wl, acc[gate], 0,0,0);
    }
  }
  #pragma unroll
  for (int gate = 0; gate < 3; ++gate)
    #pragma unroll
    for (int rg = 0; rg < 4; ++rg)
      ldsF[((wid*3 + gate)*4 + rg)*64 + lane] = acc[gate][rg];
  __syncthreads();
  if (tid < 256){
    const float* prex = (const float*)(ws + OFF_PREX);
    const float* vmw  = (const float*)(ws + OFF_VMW);
    const int l = tid & 63, rg = tid >> 6;
    const int c = c0 + (l & 15);
    const int b = g*16 + (l >> 4)*4 + rg;
    float gi[3], gh[3];
    #pragma unroll
    for (int gate = 0; gate < 3; ++gate){
      float si = 0.f, sh = 0.f;
      #pragma unroll
      for (int kq2 = 0; kq2 < 4; ++kq2){
        si += ldsF[(((2*kq2+0)*3 + gate)*4 + rg)*64 + l];
        sh += ldsF[(((2*kq2+1)*3 + gate)*4 + rg)*64 + l];
      }
      gi[gate] = si; gh[gate] = sh;
    }
    long pb = ((long)b*21 + t)*1536;
    float ir  = gi[0] + prex[pb + c]        + vmw[b*1536 + c];
    float iz  = gi[1] + prex[pb + 512 + c]  + vmw[b*1536 + 512 + c];
    float in_ = gi[2] + prex[pb + 1024 + c] + vmw[b*1536 + 1024 + c];
    float hr = gh[0] + abhh[c];
    float hz = gh[1] + abhh[512 + c];
    float hn = gh[2] + abhh[1024 + c];
    float r_ = sigm(ir + hr);
    float z_ = sigm(iz + hz);
    float n_ = tanhf(in_ + r_*hn);
    float hold = bf2f(h1hi[b*512 + c]) + bf2f(h1lo[b*512 + c]);
    float hv = (1.f - z_)*n_ + z_*hold;
    u16 hh = f2bf(hv);
    h1hiN[b*512 + c] = hh;
    h1loN[b*512 + c] = f2bf(hv - bf2f(hh));
  }
}

// ---------------- phase B: attention path only (grid 64, item b = blk) ----------
__global__ __launch_bounds__(512) void k_phaseB(char* __restrict__ ws,
    const float* __restrict__ fv,
    const float* __restrict__ fc2w, const float* __restrict__ fc2b,
    const float* __restrict__ fc3w, int pa){
  __shared__ float ldsF[768];
  const int tid = threadIdx.x;
  const int pn = pa ^ 1;
  const u16* h1hi = (const u16*)(ws + OFF_H1HI) + pn*32768;
  const u16* h1lo = (const u16*)(ws + OFF_H1LO) + pn*32768;
  const int b = blockIdx.x;
  const float* vw = (const float*)(ws + OFF_VW);
  u16* mixhi = (u16*)(ws + OFF_MIXHI);
  u16* mixlo = (u16*)(ws + OFF_MIXLO);
  float* sh1 = ldsF;          // 512
  float* hwS = ldsF + 512;    // 128
  float* sS  = ldsF + 640;    // 36
  float* aS  = ldsF + 680;    // 36
  sh1[tid] = bf2f(h1hi[b*512 + tid]) + bf2f(h1lo[b*512 + tid]);
  __syncthreads();
  { // hw[128] = h1new @ fc2^T + b
    int c = tid >> 2, q = tid & 3;
    const float4* x = (const float4*)(sh1 + q*128);
    const float4* w = (const float4*)(fc2w + c*512 + q*128);
    float s = 0.f;
    #pragma unroll 8
    for (int i = 0; i < 32; ++i){
      float4 a = x[i], ww = w[i];
      s += a.x*ww.x + a.y*ww.y + a.z*ww.z + a.w*ww.w;
    }
    s += __shfl_xor(s, 1); s += __shfl_xor(s, 2);
    if (q == 0) hwS[c] = s + fc2b[c];
  }
  __syncthreads();
  { // s[l] = tanh(vw+hw).fc3
    int jj = tid & 15, l0 = tid >> 4;
    #pragma unroll
    for (int lb = 0; lb < 64; lb += 32){
      int l = lb + l0;
      float s = 0.f;
      if (l < 36){
        const float* vr = vw + (long)b*4608 + l*128;
        #pragma unroll
        for (int k = jj*8; k < jj*8 + 8; ++k) s += tanhf(vr[k] + hwS[k]) * fc3w[k];
      }
      s += __shfl_xor(s,1); s += __shfl_xor(s,2); s += __shfl_xor(s,4); s += __shfl_xor(s,8);
      if (jj == 0 && l < 36) sS[l] = s;
    }
  }
  __syncthreads();
  if (tid == 0){
    float m = -1e30f;
    for (int l = 0; l < 36; ++l) m = fmaxf(m, sS[l]);
    float sum = 0.f;
    for (int l = 0; l < 36; ++l){ float e = __expf(sS[l] - m); aS[l] = e; sum += e; }
    float inv = 1.f / sum;
    for (int l = 0; l < 36; ++l) aS[l] *= inv;
  }
  __syncthreads();
  { // mix: 2 cols per thread
    float ax = 0.f, ay = 0.f;
    const float* base = fv + (long)b*36864 + tid*2;
    for (int l = 0; l < 36; ++l){
      float a = aS[l];
      float2 v = *(const float2*)(base + l*1024);
      ax += a*v.x; ay += a*v.y;
    }
    ushort2 hi2, lo2; u16 h;
    h = f2bf(ax); hi2.x = h; lo2.x = f2bf(ax - bf2f(h));
    h = f2bf(ay); hi2.y = h; lo2.y = f2bf(ay - bf2f(h));
    *(ushort2*)(mixhi + b*1024 + tid*2) = hi2;
    *(ushort2*)(mixlo + b*1024 + tid*2) = lo2;
  }
}

// ---------------- phase C: full lang-GRU (mix + G2 + GHH2 in-block) + combine ----
// grid 128 x 512thr. block=(g=blk>>5, c0=(blk&31)*16).
// waves 0-3: mix-GEMM K-quarter; waves 4-5: G2 (h1new) K-half; waves 6-7: GHH2 (h2) K-half.
__global__ __launch_bounds__(512) void k_phaseC(char* __restrict__ ws,
    const float* __restrict__ lbih, const float* __restrict__ lbhh, int t, int pa){
  __shared__ float ldsF[6144];
  const int blk = blockIdx.x, tid = threadIdx.x;
  const int wid = tid >> 6, lane = tid & 63, lr = lane & 15, lk = lane >> 4;
  const int pn = pa ^ 1;
  const int g = blk >> 5, c0 = (blk & 31) * 16;
  const int bA = g*16 + lr;
  const u16* lih = (const u16*)(ws + OFF_LWIHHI);
  const u16* lil = (const u16*)(ws + OFF_LWIHLO);
  f32x4 acc[3];
  #pragma unroll
  for (int i = 0; i < 3; ++i) acc[i] = (f32x4){0,0,0,0};
  const u16 *pAh, *pAl, *pW[3], *pWl[3];
  int kbase;
  if (wid < 4){
    pAh = (const u16*)(ws + OFF_MIXHI) + bA*1024;
    pAl = (const u16*)(ws + OFF_MIXLO) + bA*1024;
    #pragma unroll
    for (int gate = 0; gate < 3; ++gate){
      long r = gate*512 + c0 + lr;
      pW[gate] = lih + r*1536; pWl[gate] = lil + r*1536;
    }
    kbase = wid*256;
  } else if (wid < 6){
    pAh = (const u16*)(ws + OFF_H1HI) + pn*32768 + bA*512;
    pAl = (const u16*)(ws + OFF_H1LO) + pn*32768 + bA*512;
    #pragma unroll
    for (int gate = 0; gate < 3; ++gate){
      long r = gate*512 + c0 + lr;
      pW[gate] = lih + r*1536 + 1024; pWl[gate] = lil + r*1536 + 1024;
    }
    kbase = (wid - 4)*256;
  } else {
    pAh = (const u16*)(ws + OFF_H2HI) + pa*32768 + bA*512;
    pAl = (const u16*)(ws + OFF_H2LO) + pa*32768 + bA*512;
    const u16* lhh = (const u16*)(ws + OFF_LWHHHI);
    const u16* lhl = (const u16*)(ws + OFF_LWHHLO);
    #pragma unroll
    for (int gate = 0; gate < 3; ++gate){
      long r = gate*512 + c0 + lr;
      pW[gate] = lhh + r*512; pWl[gate] = lhl + r*512;
    }
    kbase = (wid - 6)*256;
  }
  #pragma unroll
  for (int ks = 0; ks < 8; ++ks){
    const int ko = kbase + ks*32 + lk*8;
    bf16x8 ah = *(const bf16x8*)(pAh + ko);
    bf16x8 al = *(const bf16x8*)(pAl + ko);
    #pragma unroll
    for (int gate = 0; gate < 3; ++gate){
      bf16x8 wh = *(const bf16x8*)(pW[gate] + ko);
      bf16x8 wl = *(const bf16x8*)(pWl[gate] + ko);
      acc[gate] = MFMA16(ah, wh, acc[gate], 0,0,0);
      acc[gate] = MFMA16(al, wh, acc[gate], 0,0,0);
      acc[gate] = MFMA16(ah, wl, acc[gate], 0,0,0);
    }
  }
  #pragma unroll
  for (int gate = 0; gate < 3; ++gate)
    #pragma unroll
    for (int rg = 0; rg < 4; ++rg)
      ldsF[((wid*3 + gate)*4 + rg)*64 + lane] = acc[gate][rg];
  __syncthreads();
  if (tid < 256){
    const u16* h2hiO = (const u16*)(ws + OFF_H2HI) + pa*32768;
    const u16* h2loO = (const u16*)(ws + OFF_H2LO) + pa*32768;
    u16* h2hiN = (u16*)(ws + OFF_H2HI) + pn*32768;
    u16* h2loN = (u16*)(ws + OFF_H2LO) + pn*32768;
    u16* h2bf  = (u16*)(ws + OFF_H2BF);
    const int l = tid & 63, rg = tid >> 6;
    const int c = c0 + (l & 15);
    const int b = g*16 + (l >> 4)*4 + rg;
    float gi[3], gh[3];
    #pragma unroll
    for (int gate = 0; gate < 3; ++gate){
      float sm = ldsF[((0*3 + gate)*4 + rg)*64 + l] + ldsF[((1*3 + gate)*4 + rg)*64 + l]
               + ldsF[((2*3 + gate)*4 + rg)*64 + l] + ldsF[((3*3 + gate)*4 + rg)*64 + l];
      float s2 = ldsF[((4*3 + gate)*4 + rg)*64 + l] + ldsF[((5*3 + gate)*4 + rg)*64 + l];
      float sh = ldsF[((6*3 + gate)*4 + rg)*64 + l] + ldsF[((7*3 + gate)*4 + rg)*64 + l];
      gi[gate] = sm + s2 + lbih[gate*512 + c];
      gh[gate] = sh + lbhh[gate*512 + c];
    }
    float r_ = sigm(gi[0] + gh[0]);
    float z_ = sigm(gi[1] + gh[1]);
    float n_ = tanhf(gi[2] + r_*gh[2]);
    float hold = bf2f(h2hiO[b*512 + c]) + bf2f(h2loO[b*512 + c]);
    float hv = (1.f - z_)*n_ + z_*hold;
    u16 hh = f2bf(hv);
    h2hiN[b*512 + c] = hh;
    h2loN[b*512 + c] = f2bf(hv - bf2f(hh));
    h2bf[((long)b*20 + t)*512 + c] = hh;
  }
}

// ---------------- host launch ----------------
extern "C" void kernel_launch(void* const* d_in, const int* in_sizes, int n_in,
                              void* d_out, int out_size, void* d_ws, size_t ws_size,
                              hipStream_t stream){
  const float* fv   = (const float*)d_in[0];
  const float* gt   = (const float*)d_in[2];
  const float* awih = (const float*)d_in[3];
  const float* awhh = (const float*)d_in[4];
  const float* abih = (const float*)d_in[5];
  const float* abhh = (const float*)d_in[6];
  const float* lwih = (const float*)d_in[7];
  const float* lwhh = (const float*)d_in[8];
  const float* lbih = (const float*)d_in[9];
  const float* lbhh = (const float*)d_in[10];
  const float* fc1w = (const float*)d_in[11];
  const float* fc1b = (const float*)d_in[12];
  const float* fc2w = (const float*)d_in[13];
  const float* fc2b = (const float*)d_in[14];
  const float* fc3w = (const float*)d_in[15];
  const float* dw   = (const float*)d_in[17];
  const float* db   = (const float*)d_in[18];
  char* ws = (char*)d_ws;
  float* out = (float*)d_out;

  k_prep0<<<dim3(2048), dim3(256), 0, stream>>>(fv, gt, awih, awhh, lwih, lwhh, fc1w, ws);
  k_prep_gemm<<<dim3(192), dim3(512), 0, stream>>>(ws, abih, fc1b);
  k_gemm_bf16<<<dim3(20, 11), dim3(256), 0, stream>>>(
      (const u16*)(ws + OFF_GTBF), (const u16*)(ws + OFF_WMIDBF),
      (const float*)nullptr, (float*)(ws + OFF_PREX), 1344, 1536);
  for (int t = 0; t < 20; ++t){
    int pa = t & 1;
    k_phaseA<<<dim3(128), dim3(512), 0, stream>>>(ws, abhh, t, pa);
    k_phaseB<<<dim3(64), dim3(512), 0, stream>>>(ws, fv, fc2w, fc2b, fc3w, pa);
    k_phaseC<<<dim3(128), dim3(512), 0, stream>>>(ws, lbih, lbhh, t, pa);
  }
  k_cvt_dense<<<dim3(2048), dim3(256), 0, stream>>>(dw, ws);
  k_gemm_vocab<<<dim3(2500), dim3(256), 0, stream>>>(
      (const u16*)(ws + OFF_H2BF), (const u16*)(ws + OFF_WDBF), db, out);
}